// Round 8
// baseline (157.359 us; speedup 1.0000x reference)
//
#include <hip/hip_runtime.h>

#define EMB 512
#define HEADS 8
#define HD 64
#define NSEQ 4096
#define BATCH 2
#define WINDOW 128

typedef unsigned short u16;
typedef __attribute__((ext_vector_type(8))) short bf16x8;
typedef __attribute__((ext_vector_type(4))) float f32x4;

#define XS 4194304u   // x elems (2*4096*512)
#define WS 262144u    // one weight matrix elems
#define BS 512u       // one bias elems

__device__ __forceinline__ float bf2f(u16 u) {
    union { unsigned int i; float f; } x;
    x.i = ((unsigned int)u) << 16;
    return x.f;
}

__device__ __forceinline__ u16 f2bf(float f) {
    union { float f; unsigned int i; } x;
    x.f = f;
    unsigned int i = x.i;
    unsigned int lsb = (i >> 16) & 1u;
    i += 0x7fffu + lsb;   // round-to-nearest-even
    return (u16)(i >> 16);
}

// async global -> LDS, 16B per lane. LDS dest must be wave-uniform base +
// lane*16 (our staging layout satisfies this: dest byte offset = tid*16).
__device__ __forceinline__ void gload16(const u16* g, u16* l) {
    __builtin_amdgcn_global_load_lds(
        (const __attribute__((address_space(1))) void*)g,
        (__attribute__((address_space(3))) void*)l, 16, 0, 0);
}

struct raw8 { uint4 lo, hi; };

__device__ __forceinline__ raw8 loadraw8(const void* base, size_t off, int isbf) {
    raw8 r;
    if (isbf) {
        r.lo = *(const uint4*)((const u16*)base + off);
    } else {
        const float* f = (const float*)base + off;
        r.lo = *(const uint4*)f;
        r.hi = *(const uint4*)(f + 4);
    }
    return r;
}

__device__ __forceinline__ uint4 cvt8(const raw8& r, int isbf) {
    if (isbf) return r.lo;
    const float* a = (const float*)&r.lo;
    const float* b = (const float*)&r.hi;
    uint4 o;
    o.x = (unsigned)f2bf(a[0]) | ((unsigned)f2bf(a[1]) << 16);
    o.y = (unsigned)f2bf(a[2]) | ((unsigned)f2bf(a[3]) << 16);
    o.z = (unsigned)f2bf(b[0]) | ((unsigned)f2bf(b[1]) << 16);
    o.w = (unsigned)f2bf(b[2]) | ((unsigned)f2bf(b[3]) << 16);
    return o;
}

__device__ __forceinline__ int probe_bf16(const void* p) {
    const int lane = threadIdx.x & 63;
    u16 w = ((const u16*)p)[lane * 2];
    int e = (w >> 7) & 0xff;
    bool sane = (w == 0) || (e >= 100 && e <= 140);
    unsigned long long m = __ballot(sane);
    return __popcll(m) >= 48;
}

// ---------------------------------------------------------------------------
// Pre-pass: convert x, Wq,Wk,Wv,Wo, bq,bk,bv,bo to bf16 in ws. flags[0] = x
// dtype (also the output dtype). grid: 2561 x 256.
// ---------------------------------------------------------------------------
__global__ __launch_bounds__(256)
void prepass(const void* __restrict__ x,
             const void* __restrict__ Wq, const void* __restrict__ bq,
             const void* __restrict__ Wk, const void* __restrict__ bk,
             const void* __restrict__ Wv, const void* __restrict__ bv,
             const void* __restrict__ Wo, const void* __restrict__ bo,
             u16* __restrict__ xb, u16* __restrict__ wb, u16* __restrict__ bb,
             int* __restrict__ flags)
{
    const int fx  = probe_bf16(x);
    const int fwq = probe_bf16(Wq), fbq = probe_bf16(bq);
    const int fwk = probe_bf16(Wk), fbk = probe_bf16(bk);
    const int fwv = probe_bf16(Wv), fbv = probe_bf16(bv);
    const int fwo = probe_bf16(Wo), fbo = probe_bf16(bo);
    if (blockIdx.x == 0 && threadIdx.x == 0) flags[0] = fx;

    size_t idx = ((size_t)blockIdx.x * 256 + threadIdx.x) * 8;
    const size_t T_X = XS, T_W = XS + 4 * (size_t)WS, T_ALL = T_W + 4 * (size_t)BS;
    if (idx >= T_ALL) return;

    const void* src; int fl; u16* dst; size_t off;
    if (idx < T_X) {
        src = x; fl = fx; dst = xb; off = idx;
    } else if (idx < T_W) {
        size_t w = idx - T_X;
        int wi = (int)(w / WS); off = w % WS;
        src = (wi == 0) ? Wq : (wi == 1) ? Wk : (wi == 2) ? Wv : Wo;
        fl  = (wi == 0) ? fwq : (wi == 1) ? fwk : (wi == 2) ? fwv : fwo;
        dst = wb + (size_t)wi * WS;
    } else {
        size_t b = idx - T_W;
        int bi = (int)(b / BS); off = b % BS;
        src = (bi == 0) ? bq : (bi == 1) ? bk : (bi == 2) ? bv : bo;
        fl  = (bi == 0) ? fbq : (bi == 1) ? fbk : (bi == 2) ? fbv : fbo;
        dst = bb + (size_t)bi * BS;
    }
    *(uint4*)(dst + off) = cvt8(loadraw8(src, off, fl), fl);
}

// ---------------------------------------------------------------------------
// Fused QKV projection, single-barrier double-buffer with ASYNC global->LDS
// staging (global_load_lds width 16: no VGPR round-trip, ~half the staging
// VALU; proven +35% vs reg-staging at this exact 128^2 tile). q,k ->
// [bh][n][64]; q pre-scaled. V -> TRANSPOSED [bh][d][n] via swapped MFMA
// operands for wsel==2. grid (64, 12).
// ---------------------------------------------------------------------------
__global__ __launch_bounds__(256)
void qkv_gemm(const u16* __restrict__ X, const u16* __restrict__ Wall,
              const u16* __restrict__ ball,
              u16* __restrict__ qo, u16* __restrict__ ko, u16* __restrict__ vo)
{
    __shared__ __align__(16) u16 As2[2][128 * 32];
    __shared__ __align__(16) u16 Bs2[2][128 * 32];

    const int tid  = threadIdx.x;
    const int wave = tid >> 6;
    const int lane = tid & 63;
    const int quad = lane >> 4;
    const int l16  = lane & 15;
    const int wm = wave >> 1, wn = wave & 1;

    const int m0 = blockIdx.x * 128;
    const int by = blockIdx.y;
    const int wsel = by >> 2;
    const int n0 = (by & 3) * 128;

    const u16* W  = Wall + (size_t)wsel * WS;
    const u16* bi = ball + (size_t)wsel * BS;
    const float oscale = (wsel == 0) ? 0.04419417382415922f : 1.0f;

    const u16* PA = (wsel == 2) ? W : X;
    const u16* PB = (wsel == 2) ? X : W;
    const int abase = (wsel == 2) ? n0 : m0;
    const int bbase = (wsel == 2) ? m0 : n0;

    f32x4 acc[4][4];
#pragma unroll
    for (int i = 0; i < 4; ++i)
#pragma unroll
        for (int j = 0; j < 4; ++j)
            acc[i][j] = (f32x4){0.f, 0.f, 0.f, 0.f};

    const int c1 = tid, c2 = tid + 256;
    const int r1 = c1 >> 2, k1 = (c1 & 3) * 8;
    const int r2 = c2 >> 2, k2 = (c2 & 3) * 8;

    const u16* pa1 = PA + (size_t)(abase + r1) * EMB + k1;
    const u16* pa2 = PA + (size_t)(abase + r2) * EMB + k2;
    const u16* pb1 = PB + (size_t)(bbase + r1) * EMB + k1;
    const u16* pb2 = PB + (size_t)(bbase + r2) * EMB + k2;

    // tile 0 -> buf0 (async)
    gload16(pa1, &As2[0][c1 * 8]);
    gload16(pa2, &As2[0][c2 * 8]);
    gload16(pb1, &Bs2[0][c1 * 8]);
    gload16(pb2, &Bs2[0][c2 * 8]);
    __syncthreads();   // drains vmcnt

    for (int kt = 0; kt < 16; ++kt) {
        const int cur = kt & 1;

        // async-stage next tile into the other buffer (safe: last read of
        // that buffer finished at the previous barrier)
        if (kt < 15) {
            const int kk0 = (kt + 1) * 32;
            gload16(pa1 + kk0, &As2[cur ^ 1][c1 * 8]);
            gload16(pa2 + kk0, &As2[cur ^ 1][c2 * 8]);
            gload16(pb1 + kk0, &Bs2[cur ^ 1][c1 * 8]);
            gload16(pb2 + kk0, &Bs2[cur ^ 1][c2 * 8]);
        }

        bf16x8 af[4], bfr[4];
#pragma unroll
        for (int i = 0; i < 4; ++i)
            af[i] = *(const bf16x8*)&As2[cur][(wm * 64 + i * 16 + l16) * 32 + quad * 8];
#pragma unroll
        for (int j = 0; j < 4; ++j)
            bfr[j] = *(const bf16x8*)&Bs2[cur][(wn * 64 + j * 16 + l16) * 32 + quad * 8];

#pragma unroll
        for (int i = 0; i < 4; ++i)
#pragma unroll
            for (int j = 0; j < 4; ++j)
                acc[i][j] = __builtin_amdgcn_mfma_f32_16x16x32_bf16(af[i], bfr[j], acc[i][j], 0, 0, 0);

        if (kt < 15) __syncthreads();   // drains gloads + protects buffers
    }

    if (wsel != 2) {
#pragma unroll
        for (int j = 0; j < 4; ++j) {
            const int col = n0 + wn * 64 + j * 16 + l16;
            const float bv_ = bf2f(bi[col]);
            const int h = col >> 6, d = col & 63;
            u16* out = (wsel == 0) ? qo : ko;
#pragma unroll
            for (int i = 0; i < 4; ++i) {
#pragma unroll
                for (int r = 0; r < 4; ++r) {
                    const int row = m0 + wm * 64 + i * 16 + quad * 4 + r;
                    const int b = row >> 12, n = row & 4095;
                    out[(((size_t)(b * HEADS + h) * NSEQ) + n) * HD + d] =
                        f2bf((acc[i][j][r] + bv_) * oscale);
                }
            }
        }
    } else {
#pragma unroll
        for (int i = 0; i < 4; ++i) {
#pragma unroll
            for (int r = 0; r < 4; ++r) {
                const int dglob = n0 + wm * 64 + i * 16 + quad * 4 + r;
                const float bv_ = bf2f(bi[dglob]);
                const int h = dglob >> 6, dd = dglob & 63;
#pragma unroll
                for (int j = 0; j < 4; ++j) {
                    const int ncol = m0 + wn * 64 + j * 16 + l16;
                    const int b = ncol >> 12, n = ncol & 4095;
                    vo[((size_t)(b * HEADS + h) * HD + dd) * NSEQ + n] =
                        f2bf(acc[i][j][r] + bv_);
                }
            }
        }
    }
}

// ---------------------------------------------------------------------------
// MFMA flash attention v5 (round-6 version, the measured best). q,k:
// [bh][n][64]; vt: [bh][d][n] (V^T).
//  - single-barrier double-buffered K/V staging: 5 barriers/block.
//  - fixed-max softmax (m=0) with fminf(S,40) guard; ones-row denominator
//    (static Vones).
//  - per-tile + per-wave band skips; XCD-aware swizzle.
// grid (64, 16).
// ---------------------------------------------------------------------------
#define KP 72
#define VP 72
__global__ __launch_bounds__(256)
void attn_mfma(const u16* __restrict__ q, const u16* __restrict__ k,
               const u16* __restrict__ vt, u16* __restrict__ ao)
{
    __shared__ __align__(16) u16 Ks2[2][64 * KP];
    __shared__ __align__(16) u16 Vt2[2][64 * VP];
    __shared__ __align__(16) u16 Vones[16 * VP];   // row 0 = ones, rest zeros
    __shared__ __align__(16) u16 Pb[4][16 * KP];

    const int tid  = threadIdx.x;
    const int wave = tid >> 6;
    const int lane = tid & 63;
    const int quad = lane >> 4;
    const int l16  = lane & 15;

    int wg = blockIdx.y * 64 + blockIdx.x;
    wg = (wg & 7) * 128 + (wg >> 3);       // bijective XCD swizzle (1024 = 8*128)
    const int bh = wg >> 6;
    const int q0 = (wg & 63) * 64;

    const int qw = q0 + wave * 16;
    const size_t base = (size_t)bh * NSEQ * HD;
    const bool interior = (q0 >= 128) && (q0 <= NSEQ - 192);

    if (tid < VP) {
        Vones[tid] = (u16)0x3f80;          // bf16 1.0 (denominator row)
#pragma unroll
        for (int rr = 1; rr < 16; ++rr) Vones[rr * VP + tid] = 0;
    }

    bf16x8 qa0 = *(const bf16x8*)(q + base + (size_t)(qw + l16) * HD + quad * 8);
    bf16x8 qa1 = *(const bf16x8*)(q + base + (size_t)(qw + l16) * HD + 32 + quad * 8);

    f32x4 O[4], O4;
#pragma unroll
    for (int t = 0; t < 4; ++t) O[t] = (f32x4){0.f, 0.f, 0.f, 0.f};
    O4 = (f32x4){0.f, 0.f, 0.f, 0.f};

    const int key_s[2] = { tid >> 3, (tid + 256) >> 3 };  // 0..63
    const int ch8      = (tid & 7) * 8;                   // 0..56

    // Pb column swizzle: phys col16-block = logical block ^ (row>>2 within 16)
    const int pacol = (quad * 8) ^ ((l16 >> 2) << 4);

    uint4 pkv[2], pvv[2];
    // chunk 0 -> regs -> buf0
#pragma unroll
    for (int s = 0; s < 2; ++s) {
        int kg = q0 - 128 + key_s[s];
        kg = (kg < 0) ? 0 : (kg > NSEQ - 1 ? NSEQ - 1 : kg);
        pkv[s] = *(const uint4*)(k + base + (size_t)kg * HD + ch8);
        int kc = q0 - 128 + ch8;
        kc = (kc < 0) ? 0 : (kc > NSEQ - 8 ? NSEQ - 8 : kc);
        pvv[s] = *(const uint4*)(vt + base + (size_t)key_s[s] * NSEQ + kc);
    }
#pragma unroll
    for (int s = 0; s < 2; ++s) {
        *(uint4*)&Ks2[0][key_s[s] * KP + ch8] = pkv[s];
        *(uint4*)&Vt2[0][key_s[s] * VP + ch8] = pvv[s];
    }
    // chunk 1 -> regs
#pragma unroll
    for (int s = 0; s < 2; ++s) {
        int kg = q0 - 64 + key_s[s];
        kg = (kg < 0) ? 0 : (kg > NSEQ - 1 ? NSEQ - 1 : kg);
        pkv[s] = *(const uint4*)(k + base + (size_t)kg * HD + ch8);
        int kc = q0 - 64 + ch8;
        kc = (kc < 0) ? 0 : (kc > NSEQ - 8 ? NSEQ - 8 : kc);
        pvv[s] = *(const uint4*)(vt + base + (size_t)key_s[s] * NSEQ + kc);
    }
    __syncthreads();

    for (int c = 0; c < 5; ++c) {
        const int cur = c & 1;
        const int kbase = q0 - 128 + c * 64;

        // stage chunk c+1 into the other buffer
        if (c < 4) {
#pragma unroll
            for (int s = 0; s < 2; ++s) {
                *(uint4*)&Ks2[cur ^ 1][key_s[s] * KP + ch8] = pkv[s];
                *(uint4*)&Vt2[cur ^ 1][key_s[s] * VP + ch8] = pvv[s];
            }
        }
        // issue loads for chunk c+2
        if (c < 3) {
            const int nb = kbase + 128;
#pragma unroll
            for (int s = 0; s < 2; ++s) {
                int kg = nb + key_s[s];
                kg = (kg < 0) ? 0 : (kg > NSEQ - 1 ? NSEQ - 1 : kg);
                pkv[s] = *(const uint4*)(k + base + (size_t)kg * HD + ch8);
                int kc = nb + ch8;
                kc = (kc < 0) ? 0 : (kc > NSEQ - 8 ? NSEQ - 8 : kc);
                pvv[s] = *(const uint4*)(vt + base + (size_t)key_s[s] * NSEQ + kc);
            }
        }

        const int gdk = kbase - qw;       // wave-uniform
        const bool act = (gdk <= 143) && (gdk >= -191) &&
                         (kbase > -64) && (kbase < NSEQ);
        if (act) {
            f32x4 sv[4];
#pragma unroll
            for (int t = 0; t < 4; ++t) {
                const int dk = gdk + t * 16;
                if (dk >= -143 && dk <= 143) {
                    bf16x8 b0 = *(const bf16x8*)&Ks2[cur][(t * 16 + l16) * KP + quad * 8];
                    bf16x8 b1 = *(const bf16x8*)&Ks2[cur][(t * 16 + l16) * KP + 32 + quad * 8];
                    f32x4 sacc = (f32x4){0.f, 0.f, 0.f, 0.f};
                    sacc = __builtin_amdgcn_mfma_f32_16x16x32_bf16(qa0, b0, sacc, 0, 0, 0);
                    sacc = __builtin_amdgcn_mfma_f32_16x16x32_bf16(qa1, b1, sacc, 0, 0, 0);
                    if (!interior || dk < -113 || dk > 113) {
                        const int jg = kbase + t * 16 + l16;
                        const bool jok = ((unsigned)jg) < (unsigned)NSEQ;
#pragma unroll
                        for (int r = 0; r < 4; ++r) {
                            const int iq = qw + quad * 4 + r;
                            const bool band = ((unsigned)(iq - jg + WINDOW)) <= (unsigned)(2 * WINDOW);
                            if (!(jok && band)) sacc[r] = -1e30f;
                        }
                    }
                    sv[t] = sacc;
                } else {
                    sv[t] = (f32x4){-1e30f, -1e30f, -1e30f, -1e30f};
                }
            }

            // fixed-max softmax numerator: P = exp(min(S,40)); masked -> 0
#pragma unroll
            for (int t = 0; t < 4; ++t) {
                const int tc = (t ^ quad) * 16 + l16;   // swizzled phys column
#pragma unroll
                for (int r = 0; r < 4; ++r) {
                    const float pv = __expf(fminf(sv[t][r], 40.f));
                    Pb[wave][(quad * 4 + r) * KP + tc] = f2bf(pv);
                }
            }

#pragma unroll
            for (int ks2 = 0; ks2 < 2; ++ks2) {
                bf16x8 pa = *(const bf16x8*)&Pb[wave][l16 * KP + (pacol ^ (ks2 * 32))];
#pragma unroll
                for (int t = 0; t < 4; ++t) {
                    bf16x8 vb = *(const bf16x8*)&Vt2[cur][(t * 16 + l16) * VP + ks2 * 32 + quad * 8];
                    O[t] = __builtin_amdgcn_mfma_f32_16x16x32_bf16(pa, vb, O[t], 0, 0, 0);
                }
                bf16x8 vb4 = *(const bf16x8*)&Vones[l16 * VP + ks2 * 32 + quad * 8];
                O4 = __builtin_amdgcn_mfma_f32_16x16x32_bf16(pa, vb4, O4, 0, 0, 0);
            }
        }

        if (c < 4) __syncthreads();
    }

    const int bb = bh >> 3, hh = bh & 7;
    float rl[4];
#pragma unroll
    for (int r = 0; r < 4; ++r) {
        const float ls = __shfl(O4[r], lane & 48, 64);   // col 0 lives in lane quad*16
        rl[r] = 1.f / ls;
    }
#pragma unroll
    for (int t = 0; t < 4; ++t)
#pragma unroll
        for (int r = 0; r < 4; ++r) {
            const int iq = qw + quad * 4 + r;
            ao[((size_t)(bb * NSEQ + iq)) * EMB + hh * HD + t * 16 + l16] =
                f2bf(O[t][r] * rl[r]);
        }
}

// ---------------------------------------------------------------------------
// Output projection, single-barrier double-buffered reg-staging (unchanged
// from round 6; at 1 block/CU the in-register 2-deep prefetch hides latency
// better than a per-iter vmcnt(0) drain would). grid (64, 4).
// ---------------------------------------------------------------------------
__global__ __launch_bounds__(256)
void out_gemm(const u16* __restrict__ A, const u16* __restrict__ W,
              const u16* __restrict__ bias, void* __restrict__ out,
              const int* __restrict__ flags)
{
    __shared__ __align__(16) u16 As2[2][128 * 32];
    __shared__ __align__(16) u16 Bs2[2][128 * 32];

    const int tid  = threadIdx.x;
    const int wave = tid >> 6;
    const int lane = tid & 63;
    const int quad = lane >> 4;
    const int l16  = lane & 15;
    const int wm = wave >> 1, wn = wave & 1;

    const int m0 = blockIdx.x * 128;
    const int n0 = blockIdx.y * 128;
    const int fo = flags[0];

    f32x4 acc[4][4];
#pragma unroll
    for (int i = 0; i < 4; ++i)
#pragma unroll
        for (int j = 0; j < 4; ++j)
            acc[i][j] = (f32x4){0.f, 0.f, 0.f, 0.f};

    const int c1 = tid, c2 = tid + 256;
    const int r1 = c1 >> 2, k1 = (c1 & 3) * 8;
    const int r2 = c2 >> 2, k2 = (c2 & 3) * 8;

    uint4 a1 = *(const uint4*)(A + (size_t)(m0 + r1) * EMB + k1);
    uint4 a2 = *(const uint4*)(A + (size_t)(m0 + r2) * EMB + k2);
    uint4 b1 = *(const uint4*)(W + (size_t)(n0 + r1) * EMB + k1);
    uint4 b2 = *(const uint4*)(W + (size_t)(n0 + r2) * EMB + k2);
    *(uint4*)&As2[0][c1 * 8] = a1;
    *(uint4*)&As2[0][c2 * 8] = a2;
    *(uint4*)&Bs2[0][c1 * 8] = b1;
    *(uint4*)&Bs2[0][c2 * 8] = b2;
    a1 = *(const uint4*)(A + (size_t)(m0 + r1) * EMB + 32 + k1);
    a2 = *(const uint4*)(A + (size_t)(m0 + r2) * EMB + 32 + k2);
    b1 = *(const uint4*)(W + (size_t)(n0 + r1) * EMB + 32 + k1);
    b2 = *(const uint4*)(W + (size_t)(n0 + r2) * EMB + 32 + k2);
    __syncthreads();

    for (int kt = 0; kt < 16; ++kt) {
        const int cur = kt & 1;

        bf16x8 af[4], bfr[4];
#pragma unroll
        for (int i = 0; i < 4; ++i)
            af[i] = *(const bf16x8*)&As2[cur][(wm * 64 + i * 16 + l16) * 32 + quad * 8];
#pragma unroll
        for (int j = 0; j < 4; ++j)
            bfr[j] = *(const bf16x8*)&Bs2[cur][(wn * 64 + j * 16 + l16) * 32 + quad * 8];

        if (kt < 15) {
            *(uint4*)&As2[cur ^ 1][c1 * 8] = a1;
            *(uint4*)&As2[cur ^ 1][c2 * 8] = a2;
            *(uint4*)&Bs2[cur ^ 1][c1 * 8] = b1;
            *(uint4*)&Bs2[cur ^ 1][c2 * 8] = b2;
        }
        if (kt < 14) {
            const int kk0 = (kt + 2) * 32;
            a1 = *(const uint4*)(A + (size_t)(m0 + r1) * EMB + kk0 + k1);
            a2 = *(const uint4*)(A + (size_t)(m0 + r2) * EMB + kk0 + k2);
            b1 = *(const uint4*)(W + (size_t)(n0 + r1) * EMB + kk0 + k1);
            b2 = *(const uint4*)(W + (size_t)(n0 + r2) * EMB + kk0 + k2);
        }

#pragma unroll
        for (int i = 0; i < 4; ++i)
#pragma unroll
            for (int j = 0; j < 4; ++j)
                acc[i][j] = __builtin_amdgcn_mfma_f32_16x16x32_bf16(af[i], bfr[j], acc[i][j], 0, 0, 0);

        if (kt < 15) __syncthreads();
    }

#pragma unroll
    for (int j = 0; j < 4; ++j) {
        const int col = n0 + wn * 64 + j * 16 + l16;
        const float bv_ = bf2f(bias[col]);
#pragma unroll
        for (int i = 0; i < 4; ++i) {
#pragma unroll
            for (int r = 0; r < 4; ++r) {
                const int row = m0 + wm * 64 + i * 16 + quad * 4 + r;
                const float val = acc[i][j][r] + bv_;
                const size_t idx = (size_t)row * EMB + col;
                if (fo) ((u16*)out)[idx] = f2bf(val);
                else    ((float*)out)[idx] = val;
            }
        }
    }
}

extern "C" void kernel_launch(void* const* d_in, const int* in_sizes, int n_in,
                              void* d_out, int out_size, void* d_ws, size_t ws_size,
                              hipStream_t stream)
{
    const size_t HSZ  = (size_t)BATCH * HEADS * NSEQ * HD;   // 4.19M elems
    char* base = (char*)d_ws;
    int* flags = (int*)base;
    const size_t off = 256;

    u16* xb = (u16*)(base + off);            // 4.19M elems
    u16* wb = xb + XS;                       // 4 * 262144
    u16* bb = wb + 4 * (size_t)WS;           // 4 * 512
    u16* kk = bb + 4 * (size_t)BS;           // k
    u16* vv = kk + HSZ;                      // v (TRANSPOSED [bh][d][n])
    u16* ao = vv + HSZ;                      // ao
    u16* qq = ao + HSZ;                      // q (tier-1)

    const size_t need_t1 = off + 2 * (XS + 4 * (size_t)WS + 4 * (size_t)BS + 4 * HSZ);
    if (ws_size < need_t1) {
        qq = (u16*)d_out;                    // q dead before out_gemm writes d_out
    }

    prepass<<<dim3(2561), 256, 0, stream>>>(d_in[0], d_in[1], d_in[2], d_in[3],
                                            d_in[4], d_in[5], d_in[6], d_in[7],
                                            d_in[8], xb, wb, bb, flags);
    qkv_gemm<<<dim3(64, 12), 256, 0, stream>>>(xb, wb, bb, qq, kk, vv);
    attn_mfma<<<dim3(64, 16), 256, 0, stream>>>(qq, kk, vv, ao);
    out_gemm<<<dim3(64, 4), 256, 0, stream>>>(ao, wb + 3 * (size_t)WS, bb + 3 * (size_t)BS,
                                              d_out, flags);
}

// Round 9
// 150.424 us; speedup vs baseline: 1.0461x; 1.0461x over previous
//
#include <hip/hip_runtime.h>

#define EMB 512
#define HEADS 8
#define HD 64
#define NSEQ 4096
#define BATCH 2
#define WINDOW 128

typedef unsigned short u16;
typedef __attribute__((ext_vector_type(8))) short bf16x8;
typedef __attribute__((ext_vector_type(4))) float f32x4;

#define XS 4194304u   // x elems (2*4096*512)
#define WS 262144u    // one weight matrix elems
#define BS 512u       // one bias elems

__device__ __forceinline__ float bf2f(u16 u) {
    union { unsigned int i; float f; } x;
    x.i = ((unsigned int)u) << 16;
    return x.f;
}

__device__ __forceinline__ u16 f2bf(float f) {
    union { float f; unsigned int i; } x;
    x.f = f;
    unsigned int i = x.i;
    unsigned int lsb = (i >> 16) & 1u;
    i += 0x7fffu + lsb;   // round-to-nearest-even
    return (u16)(i >> 16);
}

struct raw8 { uint4 lo, hi; };

__device__ __forceinline__ raw8 loadraw8(const void* base, size_t off, int isbf) {
    raw8 r;
    if (isbf) {
        r.lo = *(const uint4*)((const u16*)base + off);
    } else {
        const float* f = (const float*)base + off;
        r.lo = *(const uint4*)f;
        r.hi = *(const uint4*)(f + 4);
    }
    return r;
}

__device__ __forceinline__ uint4 cvt8(const raw8& r, int isbf) {
    if (isbf) return r.lo;
    const float* a = (const float*)&r.lo;
    const float* b = (const float*)&r.hi;
    uint4 o;
    o.x = (unsigned)f2bf(a[0]) | ((unsigned)f2bf(a[1]) << 16);
    o.y = (unsigned)f2bf(a[2]) | ((unsigned)f2bf(a[3]) << 16);
    o.z = (unsigned)f2bf(b[0]) | ((unsigned)f2bf(b[1]) << 16);
    o.w = (unsigned)f2bf(b[2]) | ((unsigned)f2bf(b[3]) << 16);
    return o;
}

__device__ __forceinline__ int probe_bf16(const void* p) {
    const int lane = threadIdx.x & 63;
    u16 w = ((const u16*)p)[lane * 2];
    int e = (w >> 7) & 0xff;
    bool sane = (w == 0) || (e >= 100 && e <= 140);
    unsigned long long m = __ballot(sane);
    return __popcll(m) >= 48;
}

// ---------------------------------------------------------------------------
// Pre-pass: convert x, Wq,Wk,Wv,Wo, bq,bk,bv,bo to bf16 in ws. flags[0] = x
// dtype (also the output dtype). grid: 2561 x 256.
// ---------------------------------------------------------------------------
__global__ __launch_bounds__(256)
void prepass(const void* __restrict__ x,
             const void* __restrict__ Wq, const void* __restrict__ bq,
             const void* __restrict__ Wk, const void* __restrict__ bk,
             const void* __restrict__ Wv, const void* __restrict__ bv,
             const void* __restrict__ Wo, const void* __restrict__ bo,
             u16* __restrict__ xb, u16* __restrict__ wb, u16* __restrict__ bb,
             int* __restrict__ flags)
{
    const int fx  = probe_bf16(x);
    const int fwq = probe_bf16(Wq), fbq = probe_bf16(bq);
    const int fwk = probe_bf16(Wk), fbk = probe_bf16(bk);
    const int fwv = probe_bf16(Wv), fbv = probe_bf16(bv);
    const int fwo = probe_bf16(Wo), fbo = probe_bf16(bo);
    if (blockIdx.x == 0 && threadIdx.x == 0) flags[0] = fx;

    size_t idx = ((size_t)blockIdx.x * 256 + threadIdx.x) * 8;
    const size_t T_X = XS, T_W = XS + 4 * (size_t)WS, T_ALL = T_W + 4 * (size_t)BS;
    if (idx >= T_ALL) return;

    const void* src; int fl; u16* dst; size_t off;
    if (idx < T_X) {
        src = x; fl = fx; dst = xb; off = idx;
    } else if (idx < T_W) {
        size_t w = idx - T_X;
        int wi = (int)(w / WS); off = w % WS;
        src = (wi == 0) ? Wq : (wi == 1) ? Wk : (wi == 2) ? Wv : Wo;
        fl  = (wi == 0) ? fwq : (wi == 1) ? fwk : (wi == 2) ? fwv : fwo;
        dst = wb + (size_t)wi * WS;
    } else {
        size_t b = idx - T_W;
        int bi = (int)(b / BS); off = b % BS;
        src = (bi == 0) ? bq : (bi == 1) ? bk : (bi == 2) ? bv : bo;
        fl  = (bi == 0) ? fbq : (bi == 1) ? fbk : (bi == 2) ? fbv : fbo;
        dst = bb + (size_t)bi * BS;
    }
    *(uint4*)(dst + off) = cvt8(loadraw8(src, off, fl), fl);
}

// ---------------------------------------------------------------------------
// Fused QKV projection, single-barrier double-buffered LDS with 2-deep
// REGISTER prefetch (R6-proven; reg prefetch survives barriers because its
// waitcnt lands at the ds_write use, unlike global_load_lds which forces a
// vmcnt(0) drain at every barrier -- R8 measured that 7 us slower).
// q,k -> [bh][n][64]; q pre-scaled. V -> TRANSPOSED [bh][d][n] via swapped
// MFMA operands for wsel==2. grid (64, 12).
// ---------------------------------------------------------------------------
__global__ __launch_bounds__(256)
void qkv_gemm(const u16* __restrict__ X, const u16* __restrict__ Wall,
              const u16* __restrict__ ball,
              u16* __restrict__ qo, u16* __restrict__ ko, u16* __restrict__ vo)
{
    __shared__ __align__(16) u16 As2[2][128 * 32];
    __shared__ __align__(16) u16 Bs2[2][128 * 32];

    const int tid  = threadIdx.x;
    const int wave = tid >> 6;
    const int lane = tid & 63;
    const int quad = lane >> 4;
    const int l16  = lane & 15;
    const int wm = wave >> 1, wn = wave & 1;

    const int m0 = blockIdx.x * 128;
    const int by = blockIdx.y;
    const int wsel = by >> 2;
    const int n0 = (by & 3) * 128;

    const u16* W  = Wall + (size_t)wsel * WS;
    const u16* bi = ball + (size_t)wsel * BS;
    const float oscale = (wsel == 0) ? 0.04419417382415922f : 1.0f;

    const u16* PA = (wsel == 2) ? W : X;
    const u16* PB = (wsel == 2) ? X : W;
    const int abase = (wsel == 2) ? n0 : m0;
    const int bbase = (wsel == 2) ? m0 : n0;

    f32x4 acc[4][4];
#pragma unroll
    for (int i = 0; i < 4; ++i)
#pragma unroll
        for (int j = 0; j < 4; ++j)
            acc[i][j] = (f32x4){0.f, 0.f, 0.f, 0.f};

    const int c1 = tid, c2 = tid + 256;
    const int r1 = c1 >> 2, k1 = (c1 & 3) * 8;
    const int r2 = c2 >> 2, k2 = (c2 & 3) * 8;

    uint4 a1 = *(const uint4*)(PA + (size_t)(abase + r1) * EMB + k1);
    uint4 a2 = *(const uint4*)(PA + (size_t)(abase + r2) * EMB + k2);
    uint4 b1 = *(const uint4*)(PB + (size_t)(bbase + r1) * EMB + k1);
    uint4 b2 = *(const uint4*)(PB + (size_t)(bbase + r2) * EMB + k2);
    *(uint4*)&As2[0][c1 * 8] = a1;
    *(uint4*)&As2[0][c2 * 8] = a2;
    *(uint4*)&Bs2[0][c1 * 8] = b1;
    *(uint4*)&Bs2[0][c2 * 8] = b2;
    a1 = *(const uint4*)(PA + (size_t)(abase + r1) * EMB + 32 + k1);
    a2 = *(const uint4*)(PA + (size_t)(abase + r2) * EMB + 32 + k2);
    b1 = *(const uint4*)(PB + (size_t)(bbase + r1) * EMB + 32 + k1);
    b2 = *(const uint4*)(PB + (size_t)(bbase + r2) * EMB + 32 + k2);
    __syncthreads();

    for (int kt = 0; kt < 16; ++kt) {
        const int cur = kt & 1;

        bf16x8 af[4], bfr[4];
#pragma unroll
        for (int i = 0; i < 4; ++i)
            af[i] = *(const bf16x8*)&As2[cur][(wm * 64 + i * 16 + l16) * 32 + quad * 8];
#pragma unroll
        for (int j = 0; j < 4; ++j)
            bfr[j] = *(const bf16x8*)&Bs2[cur][(wn * 64 + j * 16 + l16) * 32 + quad * 8];

        if (kt < 15) {
            *(uint4*)&As2[cur ^ 1][c1 * 8] = a1;
            *(uint4*)&As2[cur ^ 1][c2 * 8] = a2;
            *(uint4*)&Bs2[cur ^ 1][c1 * 8] = b1;
            *(uint4*)&Bs2[cur ^ 1][c2 * 8] = b2;
        }
        if (kt < 14) {
            const int kk0 = (kt + 2) * 32;
            a1 = *(const uint4*)(PA + (size_t)(abase + r1) * EMB + kk0 + k1);
            a2 = *(const uint4*)(PA + (size_t)(abase + r2) * EMB + kk0 + k2);
            b1 = *(const uint4*)(PB + (size_t)(bbase + r1) * EMB + kk0 + k1);
            b2 = *(const uint4*)(PB + (size_t)(bbase + r2) * EMB + kk0 + k2);
        }

#pragma unroll
        for (int i = 0; i < 4; ++i)
#pragma unroll
            for (int j = 0; j < 4; ++j)
                acc[i][j] = __builtin_amdgcn_mfma_f32_16x16x32_bf16(af[i], bfr[j], acc[i][j], 0, 0, 0);

        if (kt < 15) __syncthreads();
    }

    if (wsel != 2) {
#pragma unroll
        for (int j = 0; j < 4; ++j) {
            const int col = n0 + wn * 64 + j * 16 + l16;
            const float bv_ = bf2f(bi[col]);
            const int h = col >> 6, d = col & 63;
            u16* out = (wsel == 0) ? qo : ko;
#pragma unroll
            for (int i = 0; i < 4; ++i) {
#pragma unroll
                for (int r = 0; r < 4; ++r) {
                    const int row = m0 + wm * 64 + i * 16 + quad * 4 + r;
                    const int b = row >> 12, n = row & 4095;
                    out[(((size_t)(b * HEADS + h) * NSEQ) + n) * HD + d] =
                        f2bf((acc[i][j][r] + bv_) * oscale);
                }
            }
        }
    } else {
#pragma unroll
        for (int i = 0; i < 4; ++i) {
#pragma unroll
            for (int r = 0; r < 4; ++r) {
                const int dglob = n0 + wm * 64 + i * 16 + quad * 4 + r;
                const float bv_ = bf2f(bi[dglob]);
                const int h = dglob >> 6, dd = dglob & 63;
#pragma unroll
                for (int j = 0; j < 4; ++j) {
                    const int ncol = m0 + wn * 64 + j * 16 + l16;
                    const int b = ncol >> 12, n = ncol & 4095;
                    vo[((size_t)(b * HEADS + h) * HD + dd) * NSEQ + n] =
                        f2bf(acc[i][j][r] + bv_);
                }
            }
        }
    }
}

// ---------------------------------------------------------------------------
// MFMA flash attention v7 = R6 (measured best) + s_setprio around MFMA
// clusters (T5: 4 blocks/CU at independent chunk phases -> scheduler can
// favor MFMA-entering waves; +4-7% prior on attn, m191).
// q,k: [bh][n][64]; vt: [bh][d][n] (V^T). grid (64, 16).
// ---------------------------------------------------------------------------
#define KP 72
#define VP 72
__global__ __launch_bounds__(256)
void attn_mfma(const u16* __restrict__ q, const u16* __restrict__ k,
               const u16* __restrict__ vt, u16* __restrict__ ao)
{
    __shared__ __align__(16) u16 Ks2[2][64 * KP];
    __shared__ __align__(16) u16 Vt2[2][64 * VP];
    __shared__ __align__(16) u16 Vones[16 * VP];   // row 0 = ones, rest zeros
    __shared__ __align__(16) u16 Pb[4][16 * KP];

    const int tid  = threadIdx.x;
    const int wave = tid >> 6;
    const int lane = tid & 63;
    const int quad = lane >> 4;
    const int l16  = lane & 15;

    int wg = blockIdx.y * 64 + blockIdx.x;
    wg = (wg & 7) * 128 + (wg >> 3);       // bijective XCD swizzle (1024 = 8*128)
    const int bh = wg >> 6;
    const int q0 = (wg & 63) * 64;

    const int qw = q0 + wave * 16;
    const size_t base = (size_t)bh * NSEQ * HD;
    const bool interior = (q0 >= 128) && (q0 <= NSEQ - 192);

    if (tid < VP) {
        Vones[tid] = (u16)0x3f80;          // bf16 1.0 (denominator row)
#pragma unroll
        for (int rr = 1; rr < 16; ++rr) Vones[rr * VP + tid] = 0;
    }

    bf16x8 qa0 = *(const bf16x8*)(q + base + (size_t)(qw + l16) * HD + quad * 8);
    bf16x8 qa1 = *(const bf16x8*)(q + base + (size_t)(qw + l16) * HD + 32 + quad * 8);

    f32x4 O[4], O4;
#pragma unroll
    for (int t = 0; t < 4; ++t) O[t] = (f32x4){0.f, 0.f, 0.f, 0.f};
    O4 = (f32x4){0.f, 0.f, 0.f, 0.f};

    const int key_s[2] = { tid >> 3, (tid + 256) >> 3 };  // 0..63
    const int ch8      = (tid & 7) * 8;                   // 0..56

    // Pb column swizzle: phys col16-block = logical block ^ (row>>2 within 16)
    const int pacol = (quad * 8) ^ ((l16 >> 2) << 4);

    uint4 pkv[2], pvv[2];
    // chunk 0 -> regs -> buf0
#pragma unroll
    for (int s = 0; s < 2; ++s) {
        int kg = q0 - 128 + key_s[s];
        kg = (kg < 0) ? 0 : (kg > NSEQ - 1 ? NSEQ - 1 : kg);
        pkv[s] = *(const uint4*)(k + base + (size_t)kg * HD + ch8);
        int kc = q0 - 128 + ch8;
        kc = (kc < 0) ? 0 : (kc > NSEQ - 8 ? NSEQ - 8 : kc);
        pvv[s] = *(const uint4*)(vt + base + (size_t)key_s[s] * NSEQ + kc);
    }
#pragma unroll
    for (int s = 0; s < 2; ++s) {
        *(uint4*)&Ks2[0][key_s[s] * KP + ch8] = pkv[s];
        *(uint4*)&Vt2[0][key_s[s] * VP + ch8] = pvv[s];
    }
    // chunk 1 -> regs
#pragma unroll
    for (int s = 0; s < 2; ++s) {
        int kg = q0 - 64 + key_s[s];
        kg = (kg < 0) ? 0 : (kg > NSEQ - 1 ? NSEQ - 1 : kg);
        pkv[s] = *(const uint4*)(k + base + (size_t)kg * HD + ch8);
        int kc = q0 - 64 + ch8;
        kc = (kc < 0) ? 0 : (kc > NSEQ - 8 ? NSEQ - 8 : kc);
        pvv[s] = *(const uint4*)(vt + base + (size_t)key_s[s] * NSEQ + kc);
    }
    __syncthreads();

    for (int c = 0; c < 5; ++c) {
        const int cur = c & 1;
        const int kbase = q0 - 128 + c * 64;

        // stage chunk c+1 into the other buffer
        if (c < 4) {
#pragma unroll
            for (int s = 0; s < 2; ++s) {
                *(uint4*)&Ks2[cur ^ 1][key_s[s] * KP + ch8] = pkv[s];
                *(uint4*)&Vt2[cur ^ 1][key_s[s] * VP + ch8] = pvv[s];
            }
        }
        // issue loads for chunk c+2
        if (c < 3) {
            const int nb = kbase + 128;
#pragma unroll
            for (int s = 0; s < 2; ++s) {
                int kg = nb + key_s[s];
                kg = (kg < 0) ? 0 : (kg > NSEQ - 1 ? NSEQ - 1 : kg);
                pkv[s] = *(const uint4*)(k + base + (size_t)kg * HD + ch8);
                int kc = nb + ch8;
                kc = (kc < 0) ? 0 : (kc > NSEQ - 8 ? NSEQ - 8 : kc);
                pvv[s] = *(const uint4*)(vt + base + (size_t)key_s[s] * NSEQ + kc);
            }
        }

        const int gdk = kbase - qw;       // wave-uniform
        const bool act = (gdk <= 143) && (gdk >= -191) &&
                         (kbase > -64) && (kbase < NSEQ);
        if (act) {
            f32x4 sv[4];
            __builtin_amdgcn_s_setprio(1);
#pragma unroll
            for (int t = 0; t < 4; ++t) {
                const int dk = gdk + t * 16;
                if (dk >= -143 && dk <= 143) {
                    bf16x8 b0 = *(const bf16x8*)&Ks2[cur][(t * 16 + l16) * KP + quad * 8];
                    bf16x8 b1 = *(const bf16x8*)&Ks2[cur][(t * 16 + l16) * KP + 32 + quad * 8];
                    f32x4 sacc = (f32x4){0.f, 0.f, 0.f, 0.f};
                    sacc = __builtin_amdgcn_mfma_f32_16x16x32_bf16(qa0, b0, sacc, 0, 0, 0);
                    sacc = __builtin_amdgcn_mfma_f32_16x16x32_bf16(qa1, b1, sacc, 0, 0, 0);
                    if (!interior || dk < -113 || dk > 113) {
                        const int jg = kbase + t * 16 + l16;
                        const bool jok = ((unsigned)jg) < (unsigned)NSEQ;
#pragma unroll
                        for (int r = 0; r < 4; ++r) {
                            const int iq = qw + quad * 4 + r;
                            const bool band = ((unsigned)(iq - jg + WINDOW)) <= (unsigned)(2 * WINDOW);
                            if (!(jok && band)) sacc[r] = -1e30f;
                        }
                    }
                    sv[t] = sacc;
                } else {
                    sv[t] = (f32x4){-1e30f, -1e30f, -1e30f, -1e30f};
                }
            }
            __builtin_amdgcn_s_setprio(0);

            // fixed-max softmax numerator: P = exp(min(S,40)); masked -> 0
#pragma unroll
            for (int t = 0; t < 4; ++t) {
                const int tc = (t ^ quad) * 16 + l16;   // swizzled phys column
#pragma unroll
                for (int r = 0; r < 4; ++r) {
                    const float pv = __expf(fminf(sv[t][r], 40.f));
                    Pb[wave][(quad * 4 + r) * KP + tc] = f2bf(pv);
                }
            }

            __builtin_amdgcn_s_setprio(1);
#pragma unroll
            for (int ks2 = 0; ks2 < 2; ++ks2) {
                bf16x8 pa = *(const bf16x8*)&Pb[wave][l16 * KP + (pacol ^ (ks2 * 32))];
#pragma unroll
                for (int t = 0; t < 4; ++t) {
                    bf16x8 vb = *(const bf16x8*)&Vt2[cur][(t * 16 + l16) * VP + ks2 * 32 + quad * 8];
                    O[t] = __builtin_amdgcn_mfma_f32_16x16x32_bf16(pa, vb, O[t], 0, 0, 0);
                }
                bf16x8 vb4 = *(const bf16x8*)&Vones[l16 * VP + ks2 * 32 + quad * 8];
                O4 = __builtin_amdgcn_mfma_f32_16x16x32_bf16(pa, vb4, O4, 0, 0, 0);
            }
            __builtin_amdgcn_s_setprio(0);
        }

        if (c < 4) __syncthreads();
    }

    const int bb = bh >> 3, hh = bh & 7;
    float rl[4];
#pragma unroll
    for (int r = 0; r < 4; ++r) {
        const float ls = __shfl(O4[r], lane & 48, 64);   // col 0 lives in lane quad*16
        rl[r] = 1.f / ls;
    }
#pragma unroll
    for (int t = 0; t < 4; ++t)
#pragma unroll
        for (int r = 0; r < 4; ++r) {
            const int iq = qw + quad * 4 + r;
            ao[((size_t)(bb * NSEQ + iq)) * EMB + hh * HD + t * 16 + l16] =
                f2bf(O[t][r] * rl[r]);
        }
}

// ---------------------------------------------------------------------------
// Output projection, single-barrier double-buffered reg-staging (R6 verbatim).
// grid (64, 4).
// ---------------------------------------------------------------------------
__global__ __launch_bounds__(256)
void out_gemm(const u16* __restrict__ A, const u16* __restrict__ W,
              const u16* __restrict__ bias, void* __restrict__ out,
              const int* __restrict__ flags)
{
    __shared__ __align__(16) u16 As2[2][128 * 32];
    __shared__ __align__(16) u16 Bs2[2][128 * 32];

    const int tid  = threadIdx.x;
    const int wave = tid >> 6;
    const int lane = tid & 63;
    const int quad = lane >> 4;
    const int l16  = lane & 15;
    const int wm = wave >> 1, wn = wave & 1;

    const int m0 = blockIdx.x * 128;
    const int n0 = blockIdx.y * 128;
    const int fo = flags[0];

    f32x4 acc[4][4];
#pragma unroll
    for (int i = 0; i < 4; ++i)
#pragma unroll
        for (int j = 0; j < 4; ++j)
            acc[i][j] = (f32x4){0.f, 0.f, 0.f, 0.f};

    const int c1 = tid, c2 = tid + 256;
    const int r1 = c1 >> 2, k1 = (c1 & 3) * 8;
    const int r2 = c2 >> 2, k2 = (c2 & 3) * 8;

    uint4 a1 = *(const uint4*)(A + (size_t)(m0 + r1) * EMB + k1);
    uint4 a2 = *(const uint4*)(A + (size_t)(m0 + r2) * EMB + k2);
    uint4 b1 = *(const uint4*)(W + (size_t)(n0 + r1) * EMB + k1);
    uint4 b2 = *(const uint4*)(W + (size_t)(n0 + r2) * EMB + k2);
    *(uint4*)&As2[0][c1 * 8] = a1;
    *(uint4*)&As2[0][c2 * 8] = a2;
    *(uint4*)&Bs2[0][c1 * 8] = b1;
    *(uint4*)&Bs2[0][c2 * 8] = b2;
    a1 = *(const uint4*)(A + (size_t)(m0 + r1) * EMB + 32 + k1);
    a2 = *(const uint4*)(A + (size_t)(m0 + r2) * EMB + 32 + k2);
    b1 = *(const uint4*)(W + (size_t)(n0 + r1) * EMB + 32 + k1);
    b2 = *(const uint4*)(W + (size_t)(n0 + r2) * EMB + 32 + k2);
    __syncthreads();

    for (int kt = 0; kt < 16; ++kt) {
        const int cur = kt & 1;

        bf16x8 af[4], bfr[4];
#pragma unroll
        for (int i = 0; i < 4; ++i)
            af[i] = *(const bf16x8*)&As2[cur][(wm * 64 + i * 16 + l16) * 32 + quad * 8];
#pragma unroll
        for (int j = 0; j < 4; ++j)
            bfr[j] = *(const bf16x8*)&Bs2[cur][(wn * 64 + j * 16 + l16) * 32 + quad * 8];

        if (kt < 15) {
            *(uint4*)&As2[cur ^ 1][c1 * 8] = a1;
            *(uint4*)&As2[cur ^ 1][c2 * 8] = a2;
            *(uint4*)&Bs2[cur ^ 1][c1 * 8] = b1;
            *(uint4*)&Bs2[cur ^ 1][c2 * 8] = b2;
        }
        if (kt < 14) {
            const int kk0 = (kt + 2) * 32;
            a1 = *(const uint4*)(A + (size_t)(m0 + r1) * EMB + kk0 + k1);
            a2 = *(const uint4*)(A + (size_t)(m0 + r2) * EMB + kk0 + k2);
            b1 = *(const uint4*)(W + (size_t)(n0 + r1) * EMB + kk0 + k1);
            b2 = *(const uint4*)(W + (size_t)(n0 + r2) * EMB + kk0 + k2);
        }

#pragma unroll
        for (int i = 0; i < 4; ++i)
#pragma unroll
            for (int j = 0; j < 4; ++j)
                acc[i][j] = __builtin_amdgcn_mfma_f32_16x16x32_bf16(af[i], bfr[j], acc[i][j], 0, 0, 0);

        if (kt < 15) __syncthreads();
    }

#pragma unroll
    for (int j = 0; j < 4; ++j) {
        const int col = n0 + wn * 64 + j * 16 + l16;
        const float bv_ = bf2f(bias[col]);
#pragma unroll
        for (int i = 0; i < 4; ++i) {
#pragma unroll
            for (int r = 0; r < 4; ++r) {
                const int row = m0 + wm * 64 + i * 16 + quad * 4 + r;
                const float val = acc[i][j][r] + bv_;
                const size_t idx = (size_t)row * EMB + col;
                if (fo) ((u16*)out)[idx] = f2bf(val);
                else    ((float*)out)[idx] = val;
            }
        }
    }
}

extern "C" void kernel_launch(void* const* d_in, const int* in_sizes, int n_in,
                              void* d_out, int out_size, void* d_ws, size_t ws_size,
                              hipStream_t stream)
{
    const size_t HSZ  = (size_t)BATCH * HEADS * NSEQ * HD;   // 4.19M elems
    char* base = (char*)d_ws;
    int* flags = (int*)base;
    const size_t off = 256;

    u16* xb = (u16*)(base + off);            // 4.19M elems
    u16* wb = xb + XS;                       // 4 * 262144
    u16* bb = wb + 4 * (size_t)WS;           // 4 * 512
    u16* kk = bb + 4 * (size_t)BS;           // k
    u16* vv = kk + HSZ;                      // v (TRANSPOSED [bh][d][n])
    u16* ao = vv + HSZ;                      // ao
    u16* qq = ao + HSZ;                      // q (tier-1)

    const size_t need_t1 = off + 2 * (XS + 4 * (size_t)WS + 4 * (size_t)BS + 4 * HSZ);
    if (ws_size < need_t1) {
        qq = (u16*)d_out;                    // q dead before out_gemm writes d_out
    }

    prepass<<<dim3(2561), 256, 0, stream>>>(d_in[0], d_in[1], d_in[2], d_in[3],
                                            d_in[4], d_in[5], d_in[6], d_in[7],
                                            d_in[8], xb, wb, bb, flags);
    qkv_gemm<<<dim3(64, 12), 256, 0, stream>>>(xb, wb, bb, qq, kk, vv);
    attn_mfma<<<dim3(64, 16), 256, 0, stream>>>(qq, kk, vv, ao);
    out_gemm<<<dim3(64, 4), 256, 0, stream>>>(ao, wb + 3 * (size_t)WS, bb + 3 * (size_t)BS,
                                              d_out, flags);
}

// Round 10
// 148.322 us; speedup vs baseline: 1.0609x; 1.0142x over previous
//
#include <hip/hip_runtime.h>

#define EMB 512
#define HEADS 8
#define HD 64
#define NSEQ 4096
#define BATCH 2
#define WINDOW 128

typedef unsigned short u16;
typedef __attribute__((ext_vector_type(8))) short bf16x8;
typedef __attribute__((ext_vector_type(4))) float f32x4;

#define XS 4194304u   // x elems (2*4096*512)
#define WS 262144u    // one weight matrix elems
#define BS 512u       // one bias elems

__device__ __forceinline__ float bf2f(u16 u) {
    union { unsigned int i; float f; } x;
    x.i = ((unsigned int)u) << 16;
    return x.f;
}

__device__ __forceinline__ u16 f2bf(float f) {
    union { float f; unsigned int i; } x;
    x.f = f;
    unsigned int i = x.i;
    unsigned int lsb = (i >> 16) & 1u;
    i += 0x7fffu + lsb;   // round-to-nearest-even
    return (u16)(i >> 16);
}

struct raw8 { uint4 lo, hi; };

__device__ __forceinline__ raw8 loadraw8(const void* base, size_t off, int isbf) {
    raw8 r;
    if (isbf) {
        r.lo = *(const uint4*)((const u16*)base + off);
    } else {
        const float* f = (const float*)base + off;
        r.lo = *(const uint4*)f;
        r.hi = *(const uint4*)(f + 4);
    }
    return r;
}

__device__ __forceinline__ uint4 cvt8(const raw8& r, int isbf) {
    if (isbf) return r.lo;
    const float* a = (const float*)&r.lo;
    const float* b = (const float*)&r.hi;
    uint4 o;
    o.x = (unsigned)f2bf(a[0]) | ((unsigned)f2bf(a[1]) << 16);
    o.y = (unsigned)f2bf(a[2]) | ((unsigned)f2bf(a[3]) << 16);
    o.z = (unsigned)f2bf(b[0]) | ((unsigned)f2bf(b[1]) << 16);
    o.w = (unsigned)f2bf(b[2]) | ((unsigned)f2bf(b[3]) << 16);
    return o;
}

__device__ __forceinline__ int probe_bf16(const void* p) {
    const int lane = threadIdx.x & 63;
    u16 w = ((const u16*)p)[lane * 2];
    int e = (w >> 7) & 0xff;
    bool sane = (w == 0) || (e >= 100 && e <= 140);
    unsigned long long m = __ballot(sane);
    return __popcll(m) >= 48;
}

// ---------------------------------------------------------------------------
// Pre-pass: convert x, Wq,Wk,Wv,Wo, bq,bk,bv,bo to bf16 in ws. flags[0] = x
// dtype (also the output dtype). grid: 2561 x 256.
// ---------------------------------------------------------------------------
__global__ __launch_bounds__(256)
void prepass(const void* __restrict__ x,
             const void* __restrict__ Wq, const void* __restrict__ bq,
             const void* __restrict__ Wk, const void* __restrict__ bk,
             const void* __restrict__ Wv, const void* __restrict__ bv,
             const void* __restrict__ Wo, const void* __restrict__ bo,
             u16* __restrict__ xb, u16* __restrict__ wb, u16* __restrict__ bb,
             int* __restrict__ flags)
{
    const int fx  = probe_bf16(x);
    const int fwq = probe_bf16(Wq), fbq = probe_bf16(bq);
    const int fwk = probe_bf16(Wk), fbk = probe_bf16(bk);
    const int fwv = probe_bf16(Wv), fbv = probe_bf16(bv);
    const int fwo = probe_bf16(Wo), fbo = probe_bf16(bo);
    if (blockIdx.x == 0 && threadIdx.x == 0) flags[0] = fx;

    size_t idx = ((size_t)blockIdx.x * 256 + threadIdx.x) * 8;
    const size_t T_X = XS, T_W = XS + 4 * (size_t)WS, T_ALL = T_W + 4 * (size_t)BS;
    if (idx >= T_ALL) return;

    const void* src; int fl; u16* dst; size_t off;
    if (idx < T_X) {
        src = x; fl = fx; dst = xb; off = idx;
    } else if (idx < T_W) {
        size_t w = idx - T_X;
        int wi = (int)(w / WS); off = w % WS;
        src = (wi == 0) ? Wq : (wi == 1) ? Wk : (wi == 2) ? Wv : Wo;
        fl  = (wi == 0) ? fwq : (wi == 1) ? fwk : (wi == 2) ? fwv : fwo;
        dst = wb + (size_t)wi * WS;
    } else {
        size_t b = idx - T_W;
        int bi = (int)(b / BS); off = b % BS;
        src = (bi == 0) ? bq : (bi == 1) ? bk : (bi == 2) ? bv : bo;
        fl  = (bi == 0) ? fbq : (bi == 1) ? fbk : (bi == 2) ? fbv : fbo;
        dst = bb + (size_t)bi * BS;
    }
    *(uint4*)(dst + off) = cvt8(loadraw8(src, off, fl), fl);
}

// ---------------------------------------------------------------------------
// Fused QKV projection, single-barrier double-buffered LDS with 2-deep
// REGISTER prefetch (R6-proven). q,k -> [bh][n][64]; q pre-scaled.
// V -> TRANSPOSED [bh][d][n] via swapped MFMA operands for wsel==2.
// grid (64, 12).
// ---------------------------------------------------------------------------
__global__ __launch_bounds__(256)
void qkv_gemm(const u16* __restrict__ X, const u16* __restrict__ Wall,
              const u16* __restrict__ ball,
              u16* __restrict__ qo, u16* __restrict__ ko, u16* __restrict__ vo)
{
    __shared__ __align__(16) u16 As2[2][128 * 32];
    __shared__ __align__(16) u16 Bs2[2][128 * 32];

    const int tid  = threadIdx.x;
    const int wave = tid >> 6;
    const int lane = tid & 63;
    const int quad = lane >> 4;
    const int l16  = lane & 15;
    const int wm = wave >> 1, wn = wave & 1;

    const int m0 = blockIdx.x * 128;
    const int by = blockIdx.y;
    const int wsel = by >> 2;
    const int n0 = (by & 3) * 128;

    const u16* W  = Wall + (size_t)wsel * WS;
    const u16* bi = ball + (size_t)wsel * BS;
    const float oscale = (wsel == 0) ? 0.04419417382415922f : 1.0f;

    const u16* PA = (wsel == 2) ? W : X;
    const u16* PB = (wsel == 2) ? X : W;
    const int abase = (wsel == 2) ? n0 : m0;
    const int bbase = (wsel == 2) ? m0 : n0;

    f32x4 acc[4][4];
#pragma unroll
    for (int i = 0; i < 4; ++i)
#pragma unroll
        for (int j = 0; j < 4; ++j)
            acc[i][j] = (f32x4){0.f, 0.f, 0.f, 0.f};

    const int c1 = tid, c2 = tid + 256;
    const int r1 = c1 >> 2, k1 = (c1 & 3) * 8;
    const int r2 = c2 >> 2, k2 = (c2 & 3) * 8;

    uint4 a1 = *(const uint4*)(PA + (size_t)(abase + r1) * EMB + k1);
    uint4 a2 = *(const uint4*)(PA + (size_t)(abase + r2) * EMB + k2);
    uint4 b1 = *(const uint4*)(PB + (size_t)(bbase + r1) * EMB + k1);
    uint4 b2 = *(const uint4*)(PB + (size_t)(bbase + r2) * EMB + k2);
    *(uint4*)&As2[0][c1 * 8] = a1;
    *(uint4*)&As2[0][c2 * 8] = a2;
    *(uint4*)&Bs2[0][c1 * 8] = b1;
    *(uint4*)&Bs2[0][c2 * 8] = b2;
    a1 = *(const uint4*)(PA + (size_t)(abase + r1) * EMB + 32 + k1);
    a2 = *(const uint4*)(PA + (size_t)(abase + r2) * EMB + 32 + k2);
    b1 = *(const uint4*)(PB + (size_t)(bbase + r1) * EMB + 32 + k1);
    b2 = *(const uint4*)(PB + (size_t)(bbase + r2) * EMB + 32 + k2);
    __syncthreads();

    for (int kt = 0; kt < 16; ++kt) {
        const int cur = kt & 1;

        bf16x8 af[4], bfr[4];
#pragma unroll
        for (int i = 0; i < 4; ++i)
            af[i] = *(const bf16x8*)&As2[cur][(wm * 64 + i * 16 + l16) * 32 + quad * 8];
#pragma unroll
        for (int j = 0; j < 4; ++j)
            bfr[j] = *(const bf16x8*)&Bs2[cur][(wn * 64 + j * 16 + l16) * 32 + quad * 8];

        if (kt < 15) {
            *(uint4*)&As2[cur ^ 1][c1 * 8] = a1;
            *(uint4*)&As2[cur ^ 1][c2 * 8] = a2;
            *(uint4*)&Bs2[cur ^ 1][c1 * 8] = b1;
            *(uint4*)&Bs2[cur ^ 1][c2 * 8] = b2;
        }
        if (kt < 14) {
            const int kk0 = (kt + 2) * 32;
            a1 = *(const uint4*)(PA + (size_t)(abase + r1) * EMB + kk0 + k1);
            a2 = *(const uint4*)(PA + (size_t)(abase + r2) * EMB + kk0 + k2);
            b1 = *(const uint4*)(PB + (size_t)(bbase + r1) * EMB + kk0 + k1);
            b2 = *(const uint4*)(PB + (size_t)(bbase + r2) * EMB + kk0 + k2);
        }

#pragma unroll
        for (int i = 0; i < 4; ++i)
#pragma unroll
            for (int j = 0; j < 4; ++j)
                acc[i][j] = __builtin_amdgcn_mfma_f32_16x16x32_bf16(af[i], bfr[j], acc[i][j], 0, 0, 0);

        if (kt < 15) __syncthreads();
    }

    if (wsel != 2) {
#pragma unroll
        for (int j = 0; j < 4; ++j) {
            const int col = n0 + wn * 64 + j * 16 + l16;
            const float bv_ = bf2f(bi[col]);
            const int h = col >> 6, d = col & 63;
            u16* out = (wsel == 0) ? qo : ko;
#pragma unroll
            for (int i = 0; i < 4; ++i) {
#pragma unroll
                for (int r = 0; r < 4; ++r) {
                    const int row = m0 + wm * 64 + i * 16 + quad * 4 + r;
                    const int b = row >> 12, n = row & 4095;
                    out[(((size_t)(b * HEADS + h) * NSEQ) + n) * HD + d] =
                        f2bf((acc[i][j][r] + bv_) * oscale);
                }
            }
        }
    } else {
#pragma unroll
        for (int i = 0; i < 4; ++i) {
#pragma unroll
            for (int r = 0; r < 4; ++r) {
                const int dglob = n0 + wm * 64 + i * 16 + quad * 4 + r;
                const float bv_ = bf2f(bi[dglob]);
                const int h = dglob >> 6, dd = dglob & 63;
#pragma unroll
                for (int j = 0; j < 4; ++j) {
                    const int ncol = m0 + wn * 64 + j * 16 + l16;
                    const int b = ncol >> 12, n = ncol & 4095;
                    vo[((size_t)(b * HEADS + h) * HD + dd) * NSEQ + n] =
                        f2bf(acc[i][j][r] + bv_);
                }
            }
        }
    }
}

// ---------------------------------------------------------------------------
// MFMA flash attention v5 (R6 verbatim -- measured best; setprio removed
// after R9 null). q,k: [bh][n][64]; vt: [bh][d][n] (V^T). grid (64, 16).
// ---------------------------------------------------------------------------
#define KP 72
#define VP 72
__global__ __launch_bounds__(256)
void attn_mfma(const u16* __restrict__ q, const u16* __restrict__ k,
               const u16* __restrict__ vt, u16* __restrict__ ao)
{
    __shared__ __align__(16) u16 Ks2[2][64 * KP];
    __shared__ __align__(16) u16 Vt2[2][64 * VP];
    __shared__ __align__(16) u16 Vones[16 * VP];   // row 0 = ones, rest zeros
    __shared__ __align__(16) u16 Pb[4][16 * KP];

    const int tid  = threadIdx.x;
    const int wave = tid >> 6;
    const int lane = tid & 63;
    const int quad = lane >> 4;
    const int l16  = lane & 15;

    int wg = blockIdx.y * 64 + blockIdx.x;
    wg = (wg & 7) * 128 + (wg >> 3);       // bijective XCD swizzle (1024 = 8*128)
    const int bh = wg >> 6;
    const int q0 = (wg & 63) * 64;

    const int qw = q0 + wave * 16;
    const size_t base = (size_t)bh * NSEQ * HD;
    const bool interior = (q0 >= 128) && (q0 <= NSEQ - 192);

    if (tid < VP) {
        Vones[tid] = (u16)0x3f80;          // bf16 1.0 (denominator row)
#pragma unroll
        for (int rr = 1; rr < 16; ++rr) Vones[rr * VP + tid] = 0;
    }

    bf16x8 qa0 = *(const bf16x8*)(q + base + (size_t)(qw + l16) * HD + quad * 8);
    bf16x8 qa1 = *(const bf16x8*)(q + base + (size_t)(qw + l16) * HD + 32 + quad * 8);

    f32x4 O[4], O4;
#pragma unroll
    for (int t = 0; t < 4; ++t) O[t] = (f32x4){0.f, 0.f, 0.f, 0.f};
    O4 = (f32x4){0.f, 0.f, 0.f, 0.f};

    const int key_s[2] = { tid >> 3, (tid + 256) >> 3 };  // 0..63
    const int ch8      = (tid & 7) * 8;                   // 0..56

    // Pb column swizzle: phys col16-block = logical block ^ (row>>2 within 16)
    const int pacol = (quad * 8) ^ ((l16 >> 2) << 4);

    uint4 pkv[2], pvv[2];
    // chunk 0 -> regs -> buf0
#pragma unroll
    for (int s = 0; s < 2; ++s) {
        int kg = q0 - 128 + key_s[s];
        kg = (kg < 0) ? 0 : (kg > NSEQ - 1 ? NSEQ - 1 : kg);
        pkv[s] = *(const uint4*)(k + base + (size_t)kg * HD + ch8);
        int kc = q0 - 128 + ch8;
        kc = (kc < 0) ? 0 : (kc > NSEQ - 8 ? NSEQ - 8 : kc);
        pvv[s] = *(const uint4*)(vt + base + (size_t)key_s[s] * NSEQ + kc);
    }
#pragma unroll
    for (int s = 0; s < 2; ++s) {
        *(uint4*)&Ks2[0][key_s[s] * KP + ch8] = pkv[s];
        *(uint4*)&Vt2[0][key_s[s] * VP + ch8] = pvv[s];
    }
    // chunk 1 -> regs
#pragma unroll
    for (int s = 0; s < 2; ++s) {
        int kg = q0 - 64 + key_s[s];
        kg = (kg < 0) ? 0 : (kg > NSEQ - 1 ? NSEQ - 1 : kg);
        pkv[s] = *(const uint4*)(k + base + (size_t)kg * HD + ch8);
        int kc = q0 - 64 + ch8;
        kc = (kc < 0) ? 0 : (kc > NSEQ - 8 ? NSEQ - 8 : kc);
        pvv[s] = *(const uint4*)(vt + base + (size_t)key_s[s] * NSEQ + kc);
    }
    __syncthreads();

    for (int c = 0; c < 5; ++c) {
        const int cur = c & 1;
        const int kbase = q0 - 128 + c * 64;

        // stage chunk c+1 into the other buffer
        if (c < 4) {
#pragma unroll
            for (int s = 0; s < 2; ++s) {
                *(uint4*)&Ks2[cur ^ 1][key_s[s] * KP + ch8] = pkv[s];
                *(uint4*)&Vt2[cur ^ 1][key_s[s] * VP + ch8] = pvv[s];
            }
        }
        // issue loads for chunk c+2
        if (c < 3) {
            const int nb = kbase + 128;
#pragma unroll
            for (int s = 0; s < 2; ++s) {
                int kg = nb + key_s[s];
                kg = (kg < 0) ? 0 : (kg > NSEQ - 1 ? NSEQ - 1 : kg);
                pkv[s] = *(const uint4*)(k + base + (size_t)kg * HD + ch8);
                int kc = nb + ch8;
                kc = (kc < 0) ? 0 : (kc > NSEQ - 8 ? NSEQ - 8 : kc);
                pvv[s] = *(const uint4*)(vt + base + (size_t)key_s[s] * NSEQ + kc);
            }
        }

        const int gdk = kbase - qw;       // wave-uniform
        const bool act = (gdk <= 143) && (gdk >= -191) &&
                         (kbase > -64) && (kbase < NSEQ);
        if (act) {
            f32x4 sv[4];
#pragma unroll
            for (int t = 0; t < 4; ++t) {
                const int dk = gdk + t * 16;
                if (dk >= -143 && dk <= 143) {
                    bf16x8 b0 = *(const bf16x8*)&Ks2[cur][(t * 16 + l16) * KP + quad * 8];
                    bf16x8 b1 = *(const bf16x8*)&Ks2[cur][(t * 16 + l16) * KP + 32 + quad * 8];
                    f32x4 sacc = (f32x4){0.f, 0.f, 0.f, 0.f};
                    sacc = __builtin_amdgcn_mfma_f32_16x16x32_bf16(qa0, b0, sacc, 0, 0, 0);
                    sacc = __builtin_amdgcn_mfma_f32_16x16x32_bf16(qa1, b1, sacc, 0, 0, 0);
                    if (!interior || dk < -113 || dk > 113) {
                        const int jg = kbase + t * 16 + l16;
                        const bool jok = ((unsigned)jg) < (unsigned)NSEQ;
#pragma unroll
                        for (int r = 0; r < 4; ++r) {
                            const int iq = qw + quad * 4 + r;
                            const bool band = ((unsigned)(iq - jg + WINDOW)) <= (unsigned)(2 * WINDOW);
                            if (!(jok && band)) sacc[r] = -1e30f;
                        }
                    }
                    sv[t] = sacc;
                } else {
                    sv[t] = (f32x4){-1e30f, -1e30f, -1e30f, -1e30f};
                }
            }

            // fixed-max softmax numerator: P = exp(min(S,40)); masked -> 0
#pragma unroll
            for (int t = 0; t < 4; ++t) {
                const int tc = (t ^ quad) * 16 + l16;   // swizzled phys column
#pragma unroll
                for (int r = 0; r < 4; ++r) {
                    const float pv = __expf(fminf(sv[t][r], 40.f));
                    Pb[wave][(quad * 4 + r) * KP + tc] = f2bf(pv);
                }
            }

#pragma unroll
            for (int ks2 = 0; ks2 < 2; ++ks2) {
                bf16x8 pa = *(const bf16x8*)&Pb[wave][l16 * KP + (pacol ^ (ks2 * 32))];
#pragma unroll
                for (int t = 0; t < 4; ++t) {
                    bf16x8 vb = *(const bf16x8*)&Vt2[cur][(t * 16 + l16) * VP + ks2 * 32 + quad * 8];
                    O[t] = __builtin_amdgcn_mfma_f32_16x16x32_bf16(pa, vb, O[t], 0, 0, 0);
                }
                bf16x8 vb4 = *(const bf16x8*)&Vones[l16 * VP + ks2 * 32 + quad * 8];
                O4 = __builtin_amdgcn_mfma_f32_16x16x32_bf16(pa, vb4, O4, 0, 0, 0);
            }
        }

        if (c < 4) __syncthreads();
    }

    const int bb = bh >> 3, hh = bh & 7;
    float rl[4];
#pragma unroll
    for (int r = 0; r < 4; ++r) {
        const float ls = __shfl(O4[r], lane & 48, 64);   // col 0 lives in lane quad*16
        rl[r] = 1.f / ls;
    }
#pragma unroll
    for (int t = 0; t < 4; ++t)
#pragma unroll
        for (int r = 0; r < 4; ++r) {
            const int iq = qw + quad * 4 + r;
            ao[((size_t)(bb * NSEQ + iq)) * EMB + hh * HD + t * 16 + l16] =
                f2bf(O[t][r] * rl[r]);
        }
}

// ---------------------------------------------------------------------------
// Output projection v2: same 128x128 tile / single-barrier dbuf structure,
// now 512 threads (8 waves, 2x4 wave grid, per-wave 64x32, acc[4][2]).
// Doubles waves/SIMD 1 -> 2 at 1 block/CU so staging+MFMA from different
// waves co-schedule across barrier intervals (the kernel previously had the
// worst occupancy in the pipeline: 4 waves/CU). Staging: 512 thr x 8 elems
// = one 128x32 tile per matrix. LDS unchanged (32 KB). grid (64, 4).
// ---------------------------------------------------------------------------
__global__ __launch_bounds__(512)
void out_gemm(const u16* __restrict__ A, const u16* __restrict__ W,
              const u16* __restrict__ bias, void* __restrict__ out,
              const int* __restrict__ flags)
{
    __shared__ __align__(16) u16 As2[2][128 * 32];
    __shared__ __align__(16) u16 Bs2[2][128 * 32];

    const int tid  = threadIdx.x;
    const int wave = tid >> 6;           // 0..7
    const int lane = tid & 63;
    const int quad = lane >> 4;
    const int l16  = lane & 15;
    const int wm = wave >> 2, wn = wave & 3;   // 2 x 4 wave grid

    const int m0 = blockIdx.x * 128;
    const int n0 = blockIdx.y * 128;
    const int fo = flags[0];

    f32x4 acc[4][2];
#pragma unroll
    for (int i = 0; i < 4; ++i)
#pragma unroll
        for (int j = 0; j < 2; ++j)
            acc[i][j] = (f32x4){0.f, 0.f, 0.f, 0.f};

    const int r1 = tid >> 2, k1 = (tid & 3) * 8;   // 128 rows x 32 cols

    uint4 a1 = *(const uint4*)(A + (size_t)(m0 + r1) * EMB + k1);
    uint4 b1 = *(const uint4*)(W + (size_t)(n0 + r1) * EMB + k1);
    *(uint4*)&As2[0][tid * 8] = a1;
    *(uint4*)&Bs2[0][tid * 8] = b1;
    a1 = *(const uint4*)(A + (size_t)(m0 + r1) * EMB + 32 + k1);
    b1 = *(const uint4*)(W + (size_t)(n0 + r1) * EMB + 32 + k1);
    __syncthreads();

    for (int kt = 0; kt < 16; ++kt) {
        const int cur = kt & 1;

        bf16x8 af[4], bfr[2];
#pragma unroll
        for (int i = 0; i < 4; ++i)
            af[i] = *(const bf16x8*)&As2[cur][(wm * 64 + i * 16 + l16) * 32 + quad * 8];
#pragma unroll
        for (int j = 0; j < 2; ++j)
            bfr[j] = *(const bf16x8*)&Bs2[cur][(wn * 32 + j * 16 + l16) * 32 + quad * 8];

        if (kt < 15) {
            *(uint4*)&As2[cur ^ 1][tid * 8] = a1;
            *(uint4*)&Bs2[cur ^ 1][tid * 8] = b1;
        }
        if (kt < 14) {
            const int kk0 = (kt + 2) * 32;
            a1 = *(const uint4*)(A + (size_t)(m0 + r1) * EMB + kk0 + k1);
            b1 = *(const uint4*)(W + (size_t)(n0 + r1) * EMB + kk0 + k1);
        }

#pragma unroll
        for (int i = 0; i < 4; ++i)
#pragma unroll
            for (int j = 0; j < 2; ++j)
                acc[i][j] = __builtin_amdgcn_mfma_f32_16x16x32_bf16(af[i], bfr[j], acc[i][j], 0, 0, 0);

        if (kt < 15) __syncthreads();
    }

#pragma unroll
    for (int j = 0; j < 2; ++j) {
        const int col = n0 + wn * 32 + j * 16 + l16;
        const float bv_ = bf2f(bias[col]);
#pragma unroll
        for (int i = 0; i < 4; ++i) {
#pragma unroll
            for (int r = 0; r < 4; ++r) {
                const int row = m0 + wm * 64 + i * 16 + quad * 4 + r;
                const float val = acc[i][j][r] + bv_;
                const size_t idx = (size_t)row * EMB + col;
                if (fo) ((u16*)out)[idx] = f2bf(val);
                else    ((float*)out)[idx] = val;
            }
        }
    }
}

extern "C" void kernel_launch(void* const* d_in, const int* in_sizes, int n_in,
                              void* d_out, int out_size, void* d_ws, size_t ws_size,
                              hipStream_t stream)
{
    const size_t HSZ  = (size_t)BATCH * HEADS * NSEQ * HD;   // 4.19M elems
    char* base = (char*)d_ws;
    int* flags = (int*)base;
    const size_t off = 256;

    u16* xb = (u16*)(base + off);            // 4.19M elems
    u16* wb = xb + XS;                       // 4 * 262144
    u16* bb = wb + 4 * (size_t)WS;           // 4 * 512
    u16* kk = bb + 4 * (size_t)BS;           // k
    u16* vv = kk + HSZ;                      // v (TRANSPOSED [bh][d][n])
    u16* ao = vv + HSZ;                      // ao
    u16* qq = ao + HSZ;                      // q (tier-1)

    const size_t need_t1 = off + 2 * (XS + 4 * (size_t)WS + 4 * (size_t)BS + 4 * HSZ);
    if (ws_size < need_t1) {
        qq = (u16*)d_out;                    // q dead before out_gemm writes d_out
    }

    prepass<<<dim3(2561), 256, 0, stream>>>(d_in[0], d_in[1], d_in[2], d_in[3],
                                            d_in[4], d_in[5], d_in[6], d_in[7],
                                            d_in[8], xb, wb, bb, flags);
    qkv_gemm<<<dim3(64, 12), 256, 0, stream>>>(xb, wb, bb, qq, kk, vv);
    attn_mfma<<<dim3(64, 16), 256, 0, stream>>>(qq, kk, vv, ao);
    out_gemm<<<dim3(64, 4), 512, 0, stream>>>(ao, wb + 3 * (size_t)WS, bb + 3 * (size_t)BS,
                                              d_out, flags);
}

// Round 11
// 145.970 us; speedup vs baseline: 1.0780x; 1.0161x over previous
//
#include <hip/hip_runtime.h>

#define EMB 512
#define HEADS 8
#define HD 64
#define NSEQ 4096
#define BATCH 2
#define WINDOW 128

typedef unsigned short u16;
typedef __attribute__((ext_vector_type(8))) short bf16x8;
typedef __attribute__((ext_vector_type(4))) float f32x4;

#define XS 4194304u   // x elems (2*4096*512)
#define WS 262144u    // one weight matrix elems
#define BS 512u       // one bias elems

__device__ __forceinline__ float bf2f(u16 u) {
    union { unsigned int i; float f; } x;
    x.i = ((unsigned int)u) << 16;
    return x.f;
}

__device__ __forceinline__ u16 f2bf(float f) {
    union { float f; unsigned int i; } x;
    x.f = f;
    unsigned int i = x.i;
    unsigned int lsb = (i >> 16) & 1u;
    i += 0x7fffu + lsb;   // round-to-nearest-even
    return (u16)(i >> 16);
}

struct raw8 { uint4 lo, hi; };

__device__ __forceinline__ raw8 loadraw8(const void* base, size_t off, int isbf) {
    raw8 r;
    if (isbf) {
        r.lo = *(const uint4*)((const u16*)base + off);
    } else {
        const float* f = (const float*)base + off;
        r.lo = *(const uint4*)f;
        r.hi = *(const uint4*)(f + 4);
    }
    return r;
}

__device__ __forceinline__ uint4 cvt8(const raw8& r, int isbf) {
    if (isbf) return r.lo;
    const float* a = (const float*)&r.lo;
    const float* b = (const float*)&r.hi;
    uint4 o;
    o.x = (unsigned)f2bf(a[0]) | ((unsigned)f2bf(a[1]) << 16);
    o.y = (unsigned)f2bf(a[2]) | ((unsigned)f2bf(a[3]) << 16);
    o.z = (unsigned)f2bf(b[0]) | ((unsigned)f2bf(b[1]) << 16);
    o.w = (unsigned)f2bf(b[2]) | ((unsigned)f2bf(b[3]) << 16);
    return o;
}

__device__ __forceinline__ int probe_bf16(const void* p) {
    const int lane = threadIdx.x & 63;
    u16 w = ((const u16*)p)[lane * 2];
    int e = (w >> 7) & 0xff;
    bool sane = (w == 0) || (e >= 100 && e <= 140);
    unsigned long long m = __ballot(sane);
    return __popcll(m) >= 48;
}

// ---------------------------------------------------------------------------
// Pre-pass: convert x, Wq,Wk,Wv,Wo, bq,bk,bv,bo to bf16 in ws. flags[0] = x
// dtype (also the output dtype). grid: 2561 x 256.
// ---------------------------------------------------------------------------
__global__ __launch_bounds__(256)
void prepass(const void* __restrict__ x,
             const void* __restrict__ Wq, const void* __restrict__ bq,
             const void* __restrict__ Wk, const void* __restrict__ bk,
             const void* __restrict__ Wv, const void* __restrict__ bv,
             const void* __restrict__ Wo, const void* __restrict__ bo,
             u16* __restrict__ xb, u16* __restrict__ wb, u16* __restrict__ bb,
             int* __restrict__ flags)
{
    const int fx  = probe_bf16(x);
    const int fwq = probe_bf16(Wq), fbq = probe_bf16(bq);
    const int fwk = probe_bf16(Wk), fbk = probe_bf16(bk);
    const int fwv = probe_bf16(Wv), fbv = probe_bf16(bv);
    const int fwo = probe_bf16(Wo), fbo = probe_bf16(bo);
    if (blockIdx.x == 0 && threadIdx.x == 0) flags[0] = fx;

    size_t idx = ((size_t)blockIdx.x * 256 + threadIdx.x) * 8;
    const size_t T_X = XS, T_W = XS + 4 * (size_t)WS, T_ALL = T_W + 4 * (size_t)BS;
    if (idx >= T_ALL) return;

    const void* src; int fl; u16* dst; size_t off;
    if (idx < T_X) {
        src = x; fl = fx; dst = xb; off = idx;
    } else if (idx < T_W) {
        size_t w = idx - T_X;
        int wi = (int)(w / WS); off = w % WS;
        src = (wi == 0) ? Wq : (wi == 1) ? Wk : (wi == 2) ? Wv : Wo;
        fl  = (wi == 0) ? fwq : (wi == 1) ? fwk : (wi == 2) ? fwv : fwo;
        dst = wb + (size_t)wi * WS;
    } else {
        size_t b = idx - T_W;
        int bi = (int)(b / BS); off = b % BS;
        src = (bi == 0) ? bq : (bi == 1) ? bk : (bi == 2) ? bv : bo;
        fl  = (bi == 0) ? fbq : (bi == 1) ? fbk : (bi == 2) ? fbv : fbo;
        dst = bb + (size_t)bi * BS;
    }
    *(uint4*)(dst + off) = cvt8(loadraw8(src, off, fl), fl);
}

// ---------------------------------------------------------------------------
// Fused QKV projection v2: same 128x128 tile / single-barrier dbuf / 2-deep
// register prefetch, now 512 threads (8 waves, 2x4 wave grid, per-wave 64x32,
// acc[4][2]). Doubles occupancy 12 -> 24 waves/CU (same transform that won
// on out_gemm in R10). Staging: 512 thr x 1 uint4 per matrix = one 128x32
// tile. q,k -> [bh][n][64]; q pre-scaled. V -> TRANSPOSED [bh][d][n] via
// swapped MFMA operands for wsel==2. grid (64, 12).
// ---------------------------------------------------------------------------
__global__ __launch_bounds__(512)
void qkv_gemm(const u16* __restrict__ X, const u16* __restrict__ Wall,
              const u16* __restrict__ ball,
              u16* __restrict__ qo, u16* __restrict__ ko, u16* __restrict__ vo)
{
    __shared__ __align__(16) u16 As2[2][128 * 32];
    __shared__ __align__(16) u16 Bs2[2][128 * 32];

    const int tid  = threadIdx.x;
    const int wave = tid >> 6;           // 0..7
    const int lane = tid & 63;
    const int quad = lane >> 4;
    const int l16  = lane & 15;
    const int wm = wave >> 2, wn = wave & 3;   // 2 x 4 wave grid

    const int m0 = blockIdx.x * 128;
    const int by = blockIdx.y;
    const int wsel = by >> 2;
    const int n0 = (by & 3) * 128;

    const u16* W  = Wall + (size_t)wsel * WS;
    const u16* bi = ball + (size_t)wsel * BS;
    const float oscale = (wsel == 0) ? 0.04419417382415922f : 1.0f;

    const u16* PA = (wsel == 2) ? W : X;
    const u16* PB = (wsel == 2) ? X : W;
    const int abase = (wsel == 2) ? n0 : m0;
    const int bbase = (wsel == 2) ? m0 : n0;

    f32x4 acc[4][2];
#pragma unroll
    for (int i = 0; i < 4; ++i)
#pragma unroll
        for (int j = 0; j < 2; ++j)
            acc[i][j] = (f32x4){0.f, 0.f, 0.f, 0.f};

    const int r1 = tid >> 2, k1 = (tid & 3) * 8;   // 128 rows x 32 cols

    const u16* pa = PA + (size_t)(abase + r1) * EMB + k1;
    const u16* pb = PB + (size_t)(bbase + r1) * EMB + k1;

    uint4 a1 = *(const uint4*)pa;
    uint4 b1 = *(const uint4*)pb;
    *(uint4*)&As2[0][tid * 8] = a1;
    *(uint4*)&Bs2[0][tid * 8] = b1;
    a1 = *(const uint4*)(pa + 32);
    b1 = *(const uint4*)(pb + 32);
    __syncthreads();

    for (int kt = 0; kt < 16; ++kt) {
        const int cur = kt & 1;

        bf16x8 af[4], bfr[2];
#pragma unroll
        for (int i = 0; i < 4; ++i)
            af[i] = *(const bf16x8*)&As2[cur][(wm * 64 + i * 16 + l16) * 32 + quad * 8];
#pragma unroll
        for (int j = 0; j < 2; ++j)
            bfr[j] = *(const bf16x8*)&Bs2[cur][(wn * 32 + j * 16 + l16) * 32 + quad * 8];

        if (kt < 15) {
            *(uint4*)&As2[cur ^ 1][tid * 8] = a1;
            *(uint4*)&Bs2[cur ^ 1][tid * 8] = b1;
        }
        if (kt < 14) {
            const int kk0 = (kt + 2) * 32;
            a1 = *(const uint4*)(pa + kk0);
            b1 = *(const uint4*)(pb + kk0);
        }

#pragma unroll
        for (int i = 0; i < 4; ++i)
#pragma unroll
            for (int j = 0; j < 2; ++j)
                acc[i][j] = __builtin_amdgcn_mfma_f32_16x16x32_bf16(af[i], bfr[j], acc[i][j], 0, 0, 0);

        if (kt < 15) __syncthreads();
    }

    if (wsel != 2) {
#pragma unroll
        for (int j = 0; j < 2; ++j) {
            const int col = n0 + wn * 32 + j * 16 + l16;
            const float bv_ = bf2f(bi[col]);
            const int h = col >> 6, d = col & 63;
            u16* out = (wsel == 0) ? qo : ko;
#pragma unroll
            for (int i = 0; i < 4; ++i) {
#pragma unroll
                for (int r = 0; r < 4; ++r) {
                    const int row = m0 + wm * 64 + i * 16 + quad * 4 + r;
                    const int b = row >> 12, n = row & 4095;
                    out[(((size_t)(b * HEADS + h) * NSEQ) + n) * HD + d] =
                        f2bf((acc[i][j][r] + bv_) * oscale);
                }
            }
        }
    } else {
        // v (swapped): acc rows = d (W rows, wm side), cols = n (X rows, wn side)
#pragma unroll
        for (int i = 0; i < 4; ++i) {
#pragma unroll
            for (int r = 0; r < 4; ++r) {
                const int dglob = n0 + wm * 64 + i * 16 + quad * 4 + r;
                const float bv_ = bf2f(bi[dglob]);
                const int h = dglob >> 6, dd = dglob & 63;
#pragma unroll
                for (int j = 0; j < 2; ++j) {
                    const int ncol = m0 + wn * 32 + j * 16 + l16;
                    const int b = ncol >> 12, n = ncol & 4095;
                    vo[((size_t)(b * HEADS + h) * HD + dd) * NSEQ + n] =
                        f2bf(acc[i][j][r] + bv_);
                }
            }
        }
    }
}

// ---------------------------------------------------------------------------
// MFMA flash attention v5 (R6 verbatim -- measured best). q,k: [bh][n][64];
// vt: [bh][d][n] (V^T). grid (64, 16).
// ---------------------------------------------------------------------------
#define KP 72
#define VP 72
__global__ __launch_bounds__(256)
void attn_mfma(const u16* __restrict__ q, const u16* __restrict__ k,
               const u16* __restrict__ vt, u16* __restrict__ ao)
{
    __shared__ __align__(16) u16 Ks2[2][64 * KP];
    __shared__ __align__(16) u16 Vt2[2][64 * VP];
    __shared__ __align__(16) u16 Vones[16 * VP];   // row 0 = ones, rest zeros
    __shared__ __align__(16) u16 Pb[4][16 * KP];

    const int tid  = threadIdx.x;
    const int wave = tid >> 6;
    const int lane = tid & 63;
    const int quad = lane >> 4;
    const int l16  = lane & 15;

    int wg = blockIdx.y * 64 + blockIdx.x;
    wg = (wg & 7) * 128 + (wg >> 3);       // bijective XCD swizzle (1024 = 8*128)
    const int bh = wg >> 6;
    const int q0 = (wg & 63) * 64;

    const int qw = q0 + wave * 16;
    const size_t base = (size_t)bh * NSEQ * HD;
    const bool interior = (q0 >= 128) && (q0 <= NSEQ - 192);

    if (tid < VP) {
        Vones[tid] = (u16)0x3f80;          // bf16 1.0 (denominator row)
#pragma unroll
        for (int rr = 1; rr < 16; ++rr) Vones[rr * VP + tid] = 0;
    }

    bf16x8 qa0 = *(const bf16x8*)(q + base + (size_t)(qw + l16) * HD + quad * 8);
    bf16x8 qa1 = *(const bf16x8*)(q + base + (size_t)(qw + l16) * HD + 32 + quad * 8);

    f32x4 O[4], O4;
#pragma unroll
    for (int t = 0; t < 4; ++t) O[t] = (f32x4){0.f, 0.f, 0.f, 0.f};
    O4 = (f32x4){0.f, 0.f, 0.f, 0.f};

    const int key_s[2] = { tid >> 3, (tid + 256) >> 3 };  // 0..63
    const int ch8      = (tid & 7) * 8;                   // 0..56

    // Pb column swizzle: phys col16-block = logical block ^ (row>>2 within 16)
    const int pacol = (quad * 8) ^ ((l16 >> 2) << 4);

    uint4 pkv[2], pvv[2];
    // chunk 0 -> regs -> buf0
#pragma unroll
    for (int s = 0; s < 2; ++s) {
        int kg = q0 - 128 + key_s[s];
        kg = (kg < 0) ? 0 : (kg > NSEQ - 1 ? NSEQ - 1 : kg);
        pkv[s] = *(const uint4*)(k + base + (size_t)kg * HD + ch8);
        int kc = q0 - 128 + ch8;
        kc = (kc < 0) ? 0 : (kc > NSEQ - 8 ? NSEQ - 8 : kc);
        pvv[s] = *(const uint4*)(vt + base + (size_t)key_s[s] * NSEQ + kc);
    }
#pragma unroll
    for (int s = 0; s < 2; ++s) {
        *(uint4*)&Ks2[0][key_s[s] * KP + ch8] = pkv[s];
        *(uint4*)&Vt2[0][key_s[s] * VP + ch8] = pvv[s];
    }
    // chunk 1 -> regs
#pragma unroll
    for (int s = 0; s < 2; ++s) {
        int kg = q0 - 64 + key_s[s];
        kg = (kg < 0) ? 0 : (kg > NSEQ - 1 ? NSEQ - 1 : kg);
        pkv[s] = *(const uint4*)(k + base + (size_t)kg * HD + ch8);
        int kc = q0 - 64 + ch8;
        kc = (kc < 0) ? 0 : (kc > NSEQ - 8 ? NSEQ - 8 : kc);
        pvv[s] = *(const uint4*)(vt + base + (size_t)key_s[s] * NSEQ + kc);
    }
    __syncthreads();

    for (int c = 0; c < 5; ++c) {
        const int cur = c & 1;
        const int kbase = q0 - 128 + c * 64;

        // stage chunk c+1 into the other buffer
        if (c < 4) {
#pragma unroll
            for (int s = 0; s < 2; ++s) {
                *(uint4*)&Ks2[cur ^ 1][key_s[s] * KP + ch8] = pkv[s];
                *(uint4*)&Vt2[cur ^ 1][key_s[s] * VP + ch8] = pvv[s];
            }
        }
        // issue loads for chunk c+2
        if (c < 3) {
            const int nb = kbase + 128;
#pragma unroll
            for (int s = 0; s < 2; ++s) {
                int kg = nb + key_s[s];
                kg = (kg < 0) ? 0 : (kg > NSEQ - 1 ? NSEQ - 1 : kg);
                pkv[s] = *(const uint4*)(k + base + (size_t)kg * HD + ch8);
                int kc = nb + ch8;
                kc = (kc < 0) ? 0 : (kc > NSEQ - 8 ? NSEQ - 8 : kc);
                pvv[s] = *(const uint4*)(vt + base + (size_t)key_s[s] * NSEQ + kc);
            }
        }

        const int gdk = kbase - qw;       // wave-uniform
        const bool act = (gdk <= 143) && (gdk >= -191) &&
                         (kbase > -64) && (kbase < NSEQ);
        if (act) {
            f32x4 sv[4];
#pragma unroll
            for (int t = 0; t < 4; ++t) {
                const int dk = gdk + t * 16;
                if (dk >= -143 && dk <= 143) {
                    bf16x8 b0 = *(const bf16x8*)&Ks2[cur][(t * 16 + l16) * KP + quad * 8];
                    bf16x8 b1 = *(const bf16x8*)&Ks2[cur][(t * 16 + l16) * KP + 32 + quad * 8];
                    f32x4 sacc = (f32x4){0.f, 0.f, 0.f, 0.f};
                    sacc = __builtin_amdgcn_mfma_f32_16x16x32_bf16(qa0, b0, sacc, 0, 0, 0);
                    sacc = __builtin_amdgcn_mfma_f32_16x16x32_bf16(qa1, b1, sacc, 0, 0, 0);
                    if (!interior || dk < -113 || dk > 113) {
                        const int jg = kbase + t * 16 + l16;
                        const bool jok = ((unsigned)jg) < (unsigned)NSEQ;
#pragma unroll
                        for (int r = 0; r < 4; ++r) {
                            const int iq = qw + quad * 4 + r;
                            const bool band = ((unsigned)(iq - jg + WINDOW)) <= (unsigned)(2 * WINDOW);
                            if (!(jok && band)) sacc[r] = -1e30f;
                        }
                    }
                    sv[t] = sacc;
                } else {
                    sv[t] = (f32x4){-1e30f, -1e30f, -1e30f, -1e30f};
                }
            }

            // fixed-max softmax numerator: P = exp(min(S,40)); masked -> 0
#pragma unroll
            for (int t = 0; t < 4; ++t) {
                const int tc = (t ^ quad) * 16 + l16;   // swizzled phys column
#pragma unroll
                for (int r = 0; r < 4; ++r) {
                    const float pv = __expf(fminf(sv[t][r], 40.f));
                    Pb[wave][(quad * 4 + r) * KP + tc] = f2bf(pv);
                }
            }

#pragma unroll
            for (int ks2 = 0; ks2 < 2; ++ks2) {
                bf16x8 pa = *(const bf16x8*)&Pb[wave][l16 * KP + (pacol ^ (ks2 * 32))];
#pragma unroll
                for (int t = 0; t < 4; ++t) {
                    bf16x8 vb = *(const bf16x8*)&Vt2[cur][(t * 16 + l16) * VP + ks2 * 32 + quad * 8];
                    O[t] = __builtin_amdgcn_mfma_f32_16x16x32_bf16(pa, vb, O[t], 0, 0, 0);
                }
                bf16x8 vb4 = *(const bf16x8*)&Vones[l16 * VP + ks2 * 32 + quad * 8];
                O4 = __builtin_amdgcn_mfma_f32_16x16x32_bf16(pa, vb4, O4, 0, 0, 0);
            }
        }

        if (c < 4) __syncthreads();
    }

    const int bb = bh >> 3, hh = bh & 7;
    float rl[4];
#pragma unroll
    for (int r = 0; r < 4; ++r) {
        const float ls = __shfl(O4[r], lane & 48, 64);   // col 0 lives in lane quad*16
        rl[r] = 1.f / ls;
    }
#pragma unroll
    for (int t = 0; t < 4; ++t)
#pragma unroll
        for (int r = 0; r < 4; ++r) {
            const int iq = qw + quad * 4 + r;
            ao[((size_t)(bb * NSEQ + iq)) * EMB + hh * HD + t * 16 + l16] =
                f2bf(O[t][r] * rl[r]);
        }
}

// ---------------------------------------------------------------------------
// Output projection v2 (R10 verbatim -- measured win): 512 threads, 8 waves,
// per-wave 64x32, single-barrier dbuf. grid (64, 4).
// ---------------------------------------------------------------------------
__global__ __launch_bounds__(512)
void out_gemm(const u16* __restrict__ A, const u16* __restrict__ W,
              const u16* __restrict__ bias, void* __restrict__ out,
              const int* __restrict__ flags)
{
    __shared__ __align__(16) u16 As2[2][128 * 32];
    __shared__ __align__(16) u16 Bs2[2][128 * 32];

    const int tid  = threadIdx.x;
    const int wave = tid >> 6;           // 0..7
    const int lane = tid & 63;
    const int quad = lane >> 4;
    const int l16  = lane & 15;
    const int wm = wave >> 2, wn = wave & 3;   // 2 x 4 wave grid

    const int m0 = blockIdx.x * 128;
    const int n0 = blockIdx.y * 128;
    const int fo = flags[0];

    f32x4 acc[4][2];
#pragma unroll
    for (int i = 0; i < 4; ++i)
#pragma unroll
        for (int j = 0; j < 2; ++j)
            acc[i][j] = (f32x4){0.f, 0.f, 0.f, 0.f};

    const int r1 = tid >> 2, k1 = (tid & 3) * 8;   // 128 rows x 32 cols

    uint4 a1 = *(const uint4*)(A + (size_t)(m0 + r1) * EMB + k1);
    uint4 b1 = *(const uint4*)(W + (size_t)(n0 + r1) * EMB + k1);
    *(uint4*)&As2[0][tid * 8] = a1;
    *(uint4*)&Bs2[0][tid * 8] = b1;
    a1 = *(const uint4*)(A + (size_t)(m0 + r1) * EMB + 32 + k1);
    b1 = *(const uint4*)(W + (size_t)(n0 + r1) * EMB + 32 + k1);
    __syncthreads();

    for (int kt = 0; kt < 16; ++kt) {
        const int cur = kt & 1;

        bf16x8 af[4], bfr[2];
#pragma unroll
        for (int i = 0; i < 4; ++i)
            af[i] = *(const bf16x8*)&As2[cur][(wm * 64 + i * 16 + l16) * 32 + quad * 8];
#pragma unroll
        for (int j = 0; j < 2; ++j)
            bfr[j] = *(const bf16x8*)&Bs2[cur][(wn * 32 + j * 16 + l16) * 32 + quad * 8];

        if (kt < 15) {
            *(uint4*)&As2[cur ^ 1][tid * 8] = a1;
            *(uint4*)&Bs2[cur ^ 1][tid * 8] = b1;
        }
        if (kt < 14) {
            const int kk0 = (kt + 2) * 32;
            a1 = *(const uint4*)(A + (size_t)(m0 + r1) * EMB + kk0 + k1);
            b1 = *(const uint4*)(W + (size_t)(n0 + r1) * EMB + kk0 + k1);
        }

#pragma unroll
        for (int i = 0; i < 4; ++i)
#pragma unroll
            for (int j = 0; j < 2; ++j)
                acc[i][j] = __builtin_amdgcn_mfma_f32_16x16x32_bf16(af[i], bfr[j], acc[i][j], 0, 0, 0);

        if (kt < 15) __syncthreads();
    }

#pragma unroll
    for (int j = 0; j < 2; ++j) {
        const int col = n0 + wn * 32 + j * 16 + l16;
        const float bv_ = bf2f(bias[col]);
#pragma unroll
        for (int i = 0; i < 4; ++i) {
#pragma unroll
            for (int r = 0; r < 4; ++r) {
                const int row = m0 + wm * 64 + i * 16 + quad * 4 + r;
                const float val = acc[i][j][r] + bv_;
                const size_t idx = (size_t)row * EMB + col;
                if (fo) ((u16*)out)[idx] = f2bf(val);
                else    ((float*)out)[idx] = val;
            }
        }
    }
}

extern "C" void kernel_launch(void* const* d_in, const int* in_sizes, int n_in,
                              void* d_out, int out_size, void* d_ws, size_t ws_size,
                              hipStream_t stream)
{
    const size_t HSZ  = (size_t)BATCH * HEADS * NSEQ * HD;   // 4.19M elems
    char* base = (char*)d_ws;
    int* flags = (int*)base;
    const size_t off = 256;

    u16* xb = (u16*)(base + off);            // 4.19M elems
    u16* wb = xb + XS;                       // 4 * 262144
    u16* bb = wb + 4 * (size_t)WS;           // 4 * 512
    u16* kk = bb + 4 * (size_t)BS;           // k
    u16* vv = kk + HSZ;                      // v (TRANSPOSED [bh][d][n])
    u16* ao = vv + HSZ;                      // ao
    u16* qq = ao + HSZ;                      // q (tier-1)

    const size_t need_t1 = off + 2 * (XS + 4 * (size_t)WS + 4 * (size_t)BS + 4 * HSZ);
    if (ws_size < need_t1) {
        qq = (u16*)d_out;                    // q dead before out_gemm writes d_out
    }

    prepass<<<dim3(2561), 256, 0, stream>>>(d_in[0], d_in[1], d_in[2], d_in[3],
                                            d_in[4], d_in[5], d_in[6], d_in[7],
                                            d_in[8], xb, wb, bb, flags);
    qkv_gemm<<<dim3(64, 12), 512, 0, stream>>>(xb, wb, bb, qq, kk, vv);
    attn_mfma<<<dim3(64, 16), 256, 0, stream>>>(qq, kk, vv, ao);
    out_gemm<<<dim3(64, 4), 512, 0, stream>>>(ao, wb + 3 * (size_t)WS, bb + 3 * (size_t)BS,
                                              d_out, flags);
}

// Round 12
// 145.894 us; speedup vs baseline: 1.0786x; 1.0005x over previous
//
#include <hip/hip_runtime.h>

#define EMB 512
#define HEADS 8
#define HD 64
#define NSEQ 4096
#define BATCH 2
#define WINDOW 128

typedef unsigned short u16;
typedef __attribute__((ext_vector_type(8))) short bf16x8;
typedef __attribute__((ext_vector_type(4))) float f32x4;

#define XS 4194304u   // x elems (2*4096*512)
#define WS 262144u    // one weight matrix elems
#define BS 512u       // one bias elems

__device__ __forceinline__ float bf2f(u16 u) {
    union { unsigned int i; float f; } x;
    x.i = ((unsigned int)u) << 16;
    return x.f;
}

__device__ __forceinline__ u16 f2bf(float f) {
    union { float f; unsigned int i; } x;
    x.f = f;
    unsigned int i = x.i;
    unsigned int lsb = (i >> 16) & 1u;
    i += 0x7fffu + lsb;   // round-to-nearest-even
    return (u16)(i >> 16);
}

struct raw8 { uint4 lo, hi; };

__device__ __forceinline__ raw8 loadraw8(const void* base, size_t off, int isbf) {
    raw8 r;
    if (isbf) {
        r.lo = *(const uint4*)((const u16*)base + off);
    } else {
        const float* f = (const float*)base + off;
        r.lo = *(const uint4*)f;
        r.hi = *(const uint4*)(f + 4);
    }
    return r;
}

__device__ __forceinline__ uint4 cvt8(const raw8& r, int isbf) {
    if (isbf) return r.lo;
    const float* a = (const float*)&r.lo;
    const float* b = (const float*)&r.hi;
    uint4 o;
    o.x = (unsigned)f2bf(a[0]) | ((unsigned)f2bf(a[1]) << 16);
    o.y = (unsigned)f2bf(a[2]) | ((unsigned)f2bf(a[3]) << 16);
    o.z = (unsigned)f2bf(b[0]) | ((unsigned)f2bf(b[1]) << 16);
    o.w = (unsigned)f2bf(b[2]) | ((unsigned)f2bf(b[3]) << 16);
    return o;
}

__device__ __forceinline__ int probe_bf16(const void* p) {
    const int lane = threadIdx.x & 63;
    u16 w = ((const u16*)p)[lane * 2];
    int e = (w >> 7) & 0xff;
    bool sane = (w == 0) || (e >= 100 && e <= 140);
    unsigned long long m = __ballot(sane);
    return __popcll(m) >= 48;
}

// ---------------------------------------------------------------------------
// Pre-pass v2: convert x, Wq,Wk,Wv,Wo, bq,bk,bv,bo to bf16 in ws. All region
// boundaries are multiples of 512 elems, so each WAVE lies entirely in one
// source tensor -> probe ONLY that tensor (1 probe instead of 9; ballot is
// wave-complete, branch wave-uniform). flags[0] written by idx==0 (x region).
// grid: 2561 x 256.
// ---------------------------------------------------------------------------
__global__ __launch_bounds__(256)
void prepass(const void* __restrict__ x,
             const void* __restrict__ Wq, const void* __restrict__ bq,
             const void* __restrict__ Wk, const void* __restrict__ bk,
             const void* __restrict__ Wv, const void* __restrict__ bv,
             const void* __restrict__ Wo, const void* __restrict__ bo,
             u16* __restrict__ xb, u16* __restrict__ wb, u16* __restrict__ bb,
             int* __restrict__ flags)
{
    size_t idx = ((size_t)blockIdx.x * 256 + threadIdx.x) * 8;
    const size_t T_X = XS, T_W = XS + 4 * (size_t)WS, T_ALL = T_W + 4 * (size_t)BS;
    if (idx >= T_ALL) return;

    const void* src; u16* dst; size_t off;
    if (idx < T_X) {
        src = x; dst = xb; off = idx;
    } else if (idx < T_W) {
        size_t w = idx - T_X;
        int wi = (int)(w / WS); off = w % WS;
        src = (wi == 0) ? Wq : (wi == 1) ? Wk : (wi == 2) ? Wv : Wo;
        dst = wb + (size_t)wi * WS;
    } else {
        size_t b = idx - T_W;
        int bi = (int)(b / BS); off = b % BS;
        src = (bi == 0) ? bq : (bi == 1) ? bk : (bi == 2) ? bv : bo;
        dst = bb + (size_t)bi * BS;
    }
    const int fl = probe_bf16(src);
    if (idx == 0) flags[0] = fl;   // idx 0 lies in the x region -> fl == fx
    *(uint4*)(dst + off) = cvt8(loadraw8(src, off, fl), fl);
}

// ---------------------------------------------------------------------------
// Fused QKV projection v2 (R11 verbatim -- measured win): 512 threads,
// 8 waves (2x4), per-wave 64x32, single-barrier dbuf, 2-deep reg prefetch.
// q,k -> [bh][n][64]; q pre-scaled. V -> TRANSPOSED [bh][d][n] via swapped
// MFMA operands for wsel==2. grid (64, 12).
// ---------------------------------------------------------------------------
__global__ __launch_bounds__(512)
void qkv_gemm(const u16* __restrict__ X, const u16* __restrict__ Wall,
              const u16* __restrict__ ball,
              u16* __restrict__ qo, u16* __restrict__ ko, u16* __restrict__ vo)
{
    __shared__ __align__(16) u16 As2[2][128 * 32];
    __shared__ __align__(16) u16 Bs2[2][128 * 32];

    const int tid  = threadIdx.x;
    const int wave = tid >> 6;           // 0..7
    const int lane = tid & 63;
    const int quad = lane >> 4;
    const int l16  = lane & 15;
    const int wm = wave >> 2, wn = wave & 3;   // 2 x 4 wave grid

    const int m0 = blockIdx.x * 128;
    const int by = blockIdx.y;
    const int wsel = by >> 2;
    const int n0 = (by & 3) * 128;

    const u16* W  = Wall + (size_t)wsel * WS;
    const u16* bi = ball + (size_t)wsel * BS;
    const float oscale = (wsel == 0) ? 0.04419417382415922f : 1.0f;

    const u16* PA = (wsel == 2) ? W : X;
    const u16* PB = (wsel == 2) ? X : W;
    const int abase = (wsel == 2) ? n0 : m0;
    const int bbase = (wsel == 2) ? m0 : n0;

    f32x4 acc[4][2];
#pragma unroll
    for (int i = 0; i < 4; ++i)
#pragma unroll
        for (int j = 0; j < 2; ++j)
            acc[i][j] = (f32x4){0.f, 0.f, 0.f, 0.f};

    const int r1 = tid >> 2, k1 = (tid & 3) * 8;   // 128 rows x 32 cols

    const u16* pa = PA + (size_t)(abase + r1) * EMB + k1;
    const u16* pb = PB + (size_t)(bbase + r1) * EMB + k1;

    uint4 a1 = *(const uint4*)pa;
    uint4 b1 = *(const uint4*)pb;
    *(uint4*)&As2[0][tid * 8] = a1;
    *(uint4*)&Bs2[0][tid * 8] = b1;
    a1 = *(const uint4*)(pa + 32);
    b1 = *(const uint4*)(pb + 32);
    __syncthreads();

    for (int kt = 0; kt < 16; ++kt) {
        const int cur = kt & 1;

        bf16x8 af[4], bfr[2];
#pragma unroll
        for (int i = 0; i < 4; ++i)
            af[i] = *(const bf16x8*)&As2[cur][(wm * 64 + i * 16 + l16) * 32 + quad * 8];
#pragma unroll
        for (int j = 0; j < 2; ++j)
            bfr[j] = *(const bf16x8*)&Bs2[cur][(wn * 32 + j * 16 + l16) * 32 + quad * 8];

        if (kt < 15) {
            *(uint4*)&As2[cur ^ 1][tid * 8] = a1;
            *(uint4*)&Bs2[cur ^ 1][tid * 8] = b1;
        }
        if (kt < 14) {
            const int kk0 = (kt + 2) * 32;
            a1 = *(const uint4*)(pa + kk0);
            b1 = *(const uint4*)(pb + kk0);
        }

#pragma unroll
        for (int i = 0; i < 4; ++i)
#pragma unroll
            for (int j = 0; j < 2; ++j)
                acc[i][j] = __builtin_amdgcn_mfma_f32_16x16x32_bf16(af[i], bfr[j], acc[i][j], 0, 0, 0);

        if (kt < 15) __syncthreads();
    }

    if (wsel != 2) {
#pragma unroll
        for (int j = 0; j < 2; ++j) {
            const int col = n0 + wn * 32 + j * 16 + l16;
            const float bv_ = bf2f(bi[col]);
            const int h = col >> 6, d = col & 63;
            u16* out = (wsel == 0) ? qo : ko;
#pragma unroll
            for (int i = 0; i < 4; ++i) {
#pragma unroll
                for (int r = 0; r < 4; ++r) {
                    const int row = m0 + wm * 64 + i * 16 + quad * 4 + r;
                    const int b = row >> 12, n = row & 4095;
                    out[(((size_t)(b * HEADS + h) * NSEQ) + n) * HD + d] =
                        f2bf((acc[i][j][r] + bv_) * oscale);
                }
            }
        }
    } else {
        // v (swapped): acc rows = d (W rows, wm side), cols = n (X rows, wn side)
#pragma unroll
        for (int i = 0; i < 4; ++i) {
#pragma unroll
            for (int r = 0; r < 4; ++r) {
                const int dglob = n0 + wm * 64 + i * 16 + quad * 4 + r;
                const float bv_ = bf2f(bi[dglob]);
                const int h = dglob >> 6, dd = dglob & 63;
#pragma unroll
                for (int j = 0; j < 2; ++j) {
                    const int ncol = m0 + wn * 32 + j * 16 + l16;
                    const int b = ncol >> 12, n = ncol & 4095;
                    vo[((size_t)(b * HEADS + h) * HD + dd) * NSEQ + n] =
                        f2bf(acc[i][j][r] + bv_);
                }
            }
        }
    }
}

// ---------------------------------------------------------------------------
// MFMA flash attention v5 (R6 verbatim -- measured best). q,k: [bh][n][64];
// vt: [bh][d][n] (V^T). grid (64, 16).
// ---------------------------------------------------------------------------
#define KP 72
#define VP 72
__global__ __launch_bounds__(256)
void attn_mfma(const u16* __restrict__ q, const u16* __restrict__ k,
               const u16* __restrict__ vt, u16* __restrict__ ao)
{
    __shared__ __align__(16) u16 Ks2[2][64 * KP];
    __shared__ __align__(16) u16 Vt2[2][64 * VP];
    __shared__ __align__(16) u16 Vones[16 * VP];   // row 0 = ones, rest zeros
    __shared__ __align__(16) u16 Pb[4][16 * KP];

    const int tid  = threadIdx.x;
    const int wave = tid >> 6;
    const int lane = tid & 63;
    const int quad = lane >> 4;
    const int l16  = lane & 15;

    int wg = blockIdx.y * 64 + blockIdx.x;
    wg = (wg & 7) * 128 + (wg >> 3);       // bijective XCD swizzle (1024 = 8*128)
    const int bh = wg >> 6;
    const int q0 = (wg & 63) * 64;

    const int qw = q0 + wave * 16;
    const size_t base = (size_t)bh * NSEQ * HD;
    const bool interior = (q0 >= 128) && (q0 <= NSEQ - 192);

    if (tid < VP) {
        Vones[tid] = (u16)0x3f80;          // bf16 1.0 (denominator row)
#pragma unroll
        for (int rr = 1; rr < 16; ++rr) Vones[rr * VP + tid] = 0;
    }

    bf16x8 qa0 = *(const bf16x8*)(q + base + (size_t)(qw + l16) * HD + quad * 8);
    bf16x8 qa1 = *(const bf16x8*)(q + base + (size_t)(qw + l16) * HD + 32 + quad * 8);

    f32x4 O[4], O4;
#pragma unroll
    for (int t = 0; t < 4; ++t) O[t] = (f32x4){0.f, 0.f, 0.f, 0.f};
    O4 = (f32x4){0.f, 0.f, 0.f, 0.f};

    const int key_s[2] = { tid >> 3, (tid + 256) >> 3 };  // 0..63
    const int ch8      = (tid & 7) * 8;                   // 0..56

    // Pb column swizzle: phys col16-block = logical block ^ (row>>2 within 16)
    const int pacol = (quad * 8) ^ ((l16 >> 2) << 4);

    uint4 pkv[2], pvv[2];
    // chunk 0 -> regs -> buf0
#pragma unroll
    for (int s = 0; s < 2; ++s) {
        int kg = q0 - 128 + key_s[s];
        kg = (kg < 0) ? 0 : (kg > NSEQ - 1 ? NSEQ - 1 : kg);
        pkv[s] = *(const uint4*)(k + base + (size_t)kg * HD + ch8);
        int kc = q0 - 128 + ch8;
        kc = (kc < 0) ? 0 : (kc > NSEQ - 8 ? NSEQ - 8 : kc);
        pvv[s] = *(const uint4*)(vt + base + (size_t)key_s[s] * NSEQ + kc);
    }
#pragma unroll
    for (int s = 0; s < 2; ++s) {
        *(uint4*)&Ks2[0][key_s[s] * KP + ch8] = pkv[s];
        *(uint4*)&Vt2[0][key_s[s] * VP + ch8] = pvv[s];
    }
    // chunk 1 -> regs
#pragma unroll
    for (int s = 0; s < 2; ++s) {
        int kg = q0 - 64 + key_s[s];
        kg = (kg < 0) ? 0 : (kg > NSEQ - 1 ? NSEQ - 1 : kg);
        pkv[s] = *(const uint4*)(k + base + (size_t)kg * HD + ch8);
        int kc = q0 - 64 + ch8;
        kc = (kc < 0) ? 0 : (kc > NSEQ - 8 ? NSEQ - 8 : kc);
        pvv[s] = *(const uint4*)(vt + base + (size_t)key_s[s] * NSEQ + kc);
    }
    __syncthreads();

    for (int c = 0; c < 5; ++c) {
        const int cur = c & 1;
        const int kbase = q0 - 128 + c * 64;

        // stage chunk c+1 into the other buffer
        if (c < 4) {
#pragma unroll
            for (int s = 0; s < 2; ++s) {
                *(uint4*)&Ks2[cur ^ 1][key_s[s] * KP + ch8] = pkv[s];
                *(uint4*)&Vt2[cur ^ 1][key_s[s] * VP + ch8] = pvv[s];
            }
        }
        // issue loads for chunk c+2
        if (c < 3) {
            const int nb = kbase + 128;
#pragma unroll
            for (int s = 0; s < 2; ++s) {
                int kg = nb + key_s[s];
                kg = (kg < 0) ? 0 : (kg > NSEQ - 1 ? NSEQ - 1 : kg);
                pkv[s] = *(const uint4*)(k + base + (size_t)kg * HD + ch8);
                int kc = nb + ch8;
                kc = (kc < 0) ? 0 : (kc > NSEQ - 8 ? NSEQ - 8 : kc);
                pvv[s] = *(const uint4*)(vt + base + (size_t)key_s[s] * NSEQ + kc);
            }
        }

        const int gdk = kbase - qw;       // wave-uniform
        const bool act = (gdk <= 143) && (gdk >= -191) &&
                         (kbase > -64) && (kbase < NSEQ);
        if (act) {
            f32x4 sv[4];
#pragma unroll
            for (int t = 0; t < 4; ++t) {
                const int dk = gdk + t * 16;
                if (dk >= -143 && dk <= 143) {
                    bf16x8 b0 = *(const bf16x8*)&Ks2[cur][(t * 16 + l16) * KP + quad * 8];
                    bf16x8 b1 = *(const bf16x8*)&Ks2[cur][(t * 16 + l16) * KP + 32 + quad * 8];
                    f32x4 sacc = (f32x4){0.f, 0.f, 0.f, 0.f};
                    sacc = __builtin_amdgcn_mfma_f32_16x16x32_bf16(qa0, b0, sacc, 0, 0, 0);
                    sacc = __builtin_amdgcn_mfma_f32_16x16x32_bf16(qa1, b1, sacc, 0, 0, 0);
                    if (!interior || dk < -113 || dk > 113) {
                        const int jg = kbase + t * 16 + l16;
                        const bool jok = ((unsigned)jg) < (unsigned)NSEQ;
#pragma unroll
                        for (int r = 0; r < 4; ++r) {
                            const int iq = qw + quad * 4 + r;
                            const bool band = ((unsigned)(iq - jg + WINDOW)) <= (unsigned)(2 * WINDOW);
                            if (!(jok && band)) sacc[r] = -1e30f;
                        }
                    }
                    sv[t] = sacc;
                } else {
                    sv[t] = (f32x4){-1e30f, -1e30f, -1e30f, -1e30f};
                }
            }

            // fixed-max softmax numerator: P = exp(min(S,40)); masked -> 0
#pragma unroll
            for (int t = 0; t < 4; ++t) {
                const int tc = (t ^ quad) * 16 + l16;   // swizzled phys column
#pragma unroll
                for (int r = 0; r < 4; ++r) {
                    const float pv = __expf(fminf(sv[t][r], 40.f));
                    Pb[wave][(quad * 4 + r) * KP + tc] = f2bf(pv);
                }
            }

#pragma unroll
            for (int ks2 = 0; ks2 < 2; ++ks2) {
                bf16x8 pa = *(const bf16x8*)&Pb[wave][l16 * KP + (pacol ^ (ks2 * 32))];
#pragma unroll
                for (int t = 0; t < 4; ++t) {
                    bf16x8 vb = *(const bf16x8*)&Vt2[cur][(t * 16 + l16) * VP + ks2 * 32 + quad * 8];
                    O[t] = __builtin_amdgcn_mfma_f32_16x16x32_bf16(pa, vb, O[t], 0, 0, 0);
                }
                bf16x8 vb4 = *(const bf16x8*)&Vones[l16 * VP + ks2 * 32 + quad * 8];
                O4 = __builtin_amdgcn_mfma_f32_16x16x32_bf16(pa, vb4, O4, 0, 0, 0);
            }
        }

        if (c < 4) __syncthreads();
    }

    const int bb = bh >> 3, hh = bh & 7;
    float rl[4];
#pragma unroll
    for (int r = 0; r < 4; ++r) {
        const float ls = __shfl(O4[r], lane & 48, 64);   // col 0 lives in lane quad*16
        rl[r] = 1.f / ls;
    }
#pragma unroll
    for (int t = 0; t < 4; ++t)
#pragma unroll
        for (int r = 0; r < 4; ++r) {
            const int iq = qw + quad * 4 + r;
            ao[((size_t)(bb * NSEQ + iq)) * EMB + hh * HD + t * 16 + l16] =
                f2bf(O[t][r] * rl[r]);
        }
}

// ---------------------------------------------------------------------------
// Output projection v3: same 128x128 tile / single-barrier dbuf, now 1024
// threads (16 waves, 4x4 wave grid, per-wave 32x32, acc[2][2]) -> 16 waves/CU
// (4/SIMD) at 1 block/CU, doubling R10's latency-hiding capacity. Staging:
// threads 0-511 stage the A-tile (1 uint4 each), 512-1023 the B-tile
// (wave-uniform role split). LDS unchanged (32 KB). grid (64, 4).
// ---------------------------------------------------------------------------
__global__ __launch_bounds__(1024)
void out_gemm(const u16* __restrict__ A, const u16* __restrict__ W,
              const u16* __restrict__ bias, void* __restrict__ out,
              const int* __restrict__ flags)
{
    __shared__ __align__(16) u16 As2[2][128 * 32];
    __shared__ __align__(16) u16 Bs2[2][128 * 32];

    const int tid  = threadIdx.x;
    const int wave = tid >> 6;           // 0..15
    const int lane = tid & 63;
    const int quad = lane >> 4;
    const int l16  = lane & 15;
    const int wm = wave >> 2, wn = wave & 3;   // 4 x 4 wave grid

    const int m0 = blockIdx.x * 128;
    const int n0 = blockIdx.y * 128;
    const int fo = flags[0];

    f32x4 acc[2][2];
#pragma unroll
    for (int i = 0; i < 2; ++i)
#pragma unroll
        for (int j = 0; j < 2; ++j)
            acc[i][j] = (f32x4){0.f, 0.f, 0.f, 0.f};

    // staging role: first 512 threads -> A tile, last 512 -> B tile
    const int half = tid >> 9;                 // wave-uniform
    const int t2   = tid & 511;
    const int r1 = t2 >> 2, k1 = (t2 & 3) * 8; // 128 rows x 32 cols

    const u16* P = half ? (W + (size_t)(n0 + r1) * EMB + k1)
                        : (A + (size_t)(m0 + r1) * EMB + k1);

    uint4 v1 = *(const uint4*)P;
    if (half) *(uint4*)&Bs2[0][t2 * 8] = v1;
    else      *(uint4*)&As2[0][t2 * 8] = v1;
    v1 = *(const uint4*)(P + 32);
    __syncthreads();

    for (int kt = 0; kt < 16; ++kt) {
        const int cur = kt & 1;

        bf16x8 af[2], bfr[2];
#pragma unroll
        for (int i = 0; i < 2; ++i)
            af[i] = *(const bf16x8*)&As2[cur][(wm * 32 + i * 16 + l16) * 32 + quad * 8];
#pragma unroll
        for (int j = 0; j < 2; ++j)
            bfr[j] = *(const bf16x8*)&Bs2[cur][(wn * 32 + j * 16 + l16) * 32 + quad * 8];

        if (kt < 15) {
            if (half) *(uint4*)&Bs2[cur ^ 1][t2 * 8] = v1;
            else      *(uint4*)&As2[cur ^ 1][t2 * 8] = v1;
        }
        if (kt < 14) {
            v1 = *(const uint4*)(P + (kt + 2) * 32);
        }

#pragma unroll
        for (int i = 0; i < 2; ++i)
#pragma unroll
            for (int j = 0; j < 2; ++j)
                acc[i][j] = __builtin_amdgcn_mfma_f32_16x16x32_bf16(af[i], bfr[j], acc[i][j], 0, 0, 0);

        if (kt < 15) __syncthreads();
    }

#pragma unroll
    for (int j = 0; j < 2; ++j) {
        const int col = n0 + wn * 32 + j * 16 + l16;
        const float bv_ = bf2f(bias[col]);
#pragma unroll
        for (int i = 0; i < 2; ++i) {
#pragma unroll
            for (int r = 0; r < 4; ++r) {
                const int row = m0 + wm * 32 + i * 16 + quad * 4 + r;
                const float val = acc[i][j][r] + bv_;
                const size_t idx = (size_t)row * EMB + col;
                if (fo) ((u16*)out)[idx] = f2bf(val);
                else    ((float*)out)[idx] = val;
            }
        }
    }
}

extern "C" void kernel_launch(void* const* d_in, const int* in_sizes, int n_in,
                              void* d_out, int out_size, void* d_ws, size_t ws_size,
                              hipStream_t stream)
{
    const size_t HSZ  = (size_t)BATCH * HEADS * NSEQ * HD;   // 4.19M elems
    char* base = (char*)d_ws;
    int* flags = (int*)base;
    const size_t off = 256;

    u16* xb = (u16*)(base + off);            // 4.19M elems
    u16* wb = xb + XS;                       // 4 * 262144
    u16* bb = wb + 4 * (size_t)WS;           // 4 * 512
    u16* kk = bb + 4 * (size_t)BS;           // k
    u16* vv = kk + HSZ;                      // v (TRANSPOSED [bh][d][n])
    u16* ao = vv + HSZ;                      // ao
    u16* qq = ao + HSZ;                      // q (tier-1)

    const size_t need_t1 = off + 2 * (XS + 4 * (size_t)WS + 4 * (size_t)BS + 4 * HSZ);
    if (ws_size < need_t1) {
        qq = (u16*)d_out;                    // q dead before out_gemm writes d_out
    }

    prepass<<<dim3(2561), 256, 0, stream>>>(d_in[0], d_in[1], d_in[2], d_in[3],
                                            d_in[4], d_in[5], d_in[6], d_in[7],
                                            d_in[8], xb, wb, bb, flags);
    qkv_gemm<<<dim3(64, 12), 512, 0, stream>>>(xb, wb, bb, qq, kk, vv);
    attn_mfma<<<dim3(64, 16), 256, 0, stream>>>(qq, kk, vv, ao);
    out_gemm<<<dim3(64, 4), 1024, 0, stream>>>(ao, wb + 3 * (size_t)WS, bb + 3 * (size_t)BS,
                                               d_out, flags);
}